// Round 11
// baseline (249.460 us; speedup 1.0000x reference)
//
#include <hip/hip_runtime.h>
#include <hip/hip_bf16.h>

#define HID 64
#define NGRAPH 16
#define BN 32            // nodes per bucket
#define GB 8             // buckets per coarse group (256 nodes, key = col>>8)
#define MAXNB 2048
#define NCB 256          // count/scatter blocks (256 = full CU coverage)
#define NCT 1024         // count/scatter threads (r14-verified)
#define SORT_T 1024
#define SORT_CHUNK 12800 // max records per group staged in LDS (avg ~8200)

typedef __attribute__((ext_vector_type(8))) short short8;
typedef __attribute__((ext_vector_type(4))) float f32x4;

// Fixed workspace layout (float offsets; all array bases 16B-aligned for float4)
enum : int {
  OFF_V      = 1040,
  OFF_M      = 1104,                  // unused since r15 (fold kept in LDS)
  OFF_EW1    = 5200,
  OFF_EB1    = 5520,
  OFF_NW1    = 5584,
  OFF_NB1    = 9744,
  OFF_NW2    = 9808,
  OFF_NB2    = 13904,
  OFF_OW1    = 13968,
  OFF_OB1    = 18064,
  OFF_OW2    = 18128,
  OFF_OB2    = 22224,
  OFF_OW3    = 22288,
  OFF_OB3    = 26384,
  OFF_OW4    = 26448,
  OFF_OB4    = 26576,
  OFF_EW2    = 26580,
  OFF_EB2    = 30676,
  OFF_FLAGS  = 30740,                 // 2 ints: [0]=ft (1=bf16), [1]=it (1=int64)
  OFF_W1T    = 30744,                 // 512 shorts (64 feats x 8 k)
  OFF_MT     = 31000,                 // 4096 shorts (M^T bf16)
  OFF_PREP   = 33048                  // rep: 8 pooled replicas * 16*64
};

struct WPtrs { const void* p[16]; };

__device__ __forceinline__ float cv(float v) { return v; }
__device__ __forceinline__ float cv(__hip_bfloat16 v) { return __bfloat162float(v); }
__device__ __forceinline__ float b2f(unsigned short u) {
  union { unsigned u32; float f; } c;
  c.u32 = ((unsigned)u) << 16;
  return c.f;
}
__device__ __forceinline__ unsigned short f2bu(float v) {   // cold path only
  union { __hip_bfloat16 b; unsigned short u; } c;
  c.b = __float2bfloat16(v);
  return c.u;
}
// fast RNE f32->bf16 (finite inputs): 3 VALU inst
__device__ __forceinline__ unsigned short fr(float v) {
  unsigned u = __float_as_uint(v);
  u += 0x7FFFu + ((u >> 16) & 1u);
  return (unsigned short)(u >> 16);
}
// relu + RNE-pack two floats into one dword via HW cvt_pk (lo = a, hi = b).
// r21: replaces rndpack (9 VALU / 2 floats) with fmax x2 + 1 cvt_pk.
__device__ __forceinline__ unsigned cvtpk(float a, float b) {
  unsigned r;
  asm("v_cvt_pk_bf16_f32 %0, %1, %2"
      : "=v"(r) : "v"(fmaxf(a, 0.0f)), "v"(fmaxf(b, 0.0f)));
  return r;
}

// ---------------------------------------------------------------------------
// prep (r15-verified: 1024 threads, vectorized).
// ---------------------------------------------------------------------------
__global__ __launch_bounds__(1024) void prep_kernel(
    const void* xv, const void* eiv, WPtrs wp, float* ws)
{
  __shared__ int red[2];
  __shared__ int s_ft;
  __shared__ float ew2s[4096];
  __shared__ float nw1s[4096];
  const int t = threadIdx.x;
  const int lane = t & 63;

  if (t == 0) { red[0] = 0; red[1] = 0; }
  __syncthreads();
  {
    int big = 0;
    if (t < 512) {
      const unsigned el = (((const unsigned*)xv)[t] >> 7) & 0xFFu;
      big = (el >= 140u) ? 1 : 0;
    }
    #pragma unroll
    for (int o = 32; o > 0; o >>= 1) big += __shfl_xor(big, o);
    if (lane == 0 && big) atomicAdd(&red[0], big);
  }
  {
    int orv = ((const int*)eiv)[1 + 2 * t];
    #pragma unroll
    for (int o = 32; o > 0; o >>= 1) orv |= __shfl_xor(orv, o);
    if (lane == 0 && orv) atomicOr(&red[1], orv);
  }
  __syncthreads();
  if (t == 0) {
    const int ft = (red[0] < 8) ? 1 : 0;
    const int it = (red[1] == 0) ? 1 : 0;
    ((int*)(ws + OFF_FLAGS))[0] = ft;
    ((int*)(ws + OFF_FLAGS))[1] = it;
    s_ft = ft;
  }
  __syncthreads();
  const int ft = s_ft;

  const int sz[16]  = {320,64,4096,64,4160,64,4096,64,4096,64,4096,64,4096,64,128,2};
  const int dst[16] = {OFF_EW1,OFF_EB1,OFF_EW2,OFF_EB2,OFF_NW1,OFF_NB1,OFF_NW2,OFF_NB2,
                       OFF_OW1,OFF_OB1,OFF_OW2,OFF_OB2,OFF_OW3,OFF_OB3,OFF_OW4,OFF_OB4};
  for (int a = 0; a < 16; ++a) {
    const void* src = wp.p[a];
    float* d = ws + dst[a];
    const int n = sz[a];
    const int n4 = n >> 2;
    for (int i = t; i < n4; i += 1024) {
      float4 f;
      if (ft) {
        const ushort4 u4 = ((const ushort4*)src)[i];
        f.x = b2f(u4.x); f.y = b2f(u4.y); f.z = b2f(u4.z); f.w = b2f(u4.w);
      } else {
        f = ((const float4*)src)[i];
      }
      ((float4*)d)[i] = f;
      const int g = i << 2;
      if (a == 2) {
        ew2s[g] = f.x; ew2s[g + 1] = f.y; ew2s[g + 2] = f.z; ew2s[g + 3] = f.w;
      } else if (a == 4 && g >= 64) {
        nw1s[g - 64] = f.x; nw1s[g - 63] = f.y; nw1s[g - 62] = f.z; nw1s[g - 61] = f.w;
      }
    }
    for (int i = (n4 << 2) + t; i < n; i += 1024)
      d[i] = ft ? b2f(((const unsigned short*)src)[i]) : ((const float*)src)[i];
  }
  __syncthreads();

  // fold: M = EW2 @ NW1[1:], v = EB2 @ NW1[1:]  (4 outputs/thread)
  float mv[4];
  #pragma unroll
  for (int p = 0; p < 4; ++p) {
    const int idx = t + p * 1024;
    const int i = idx >> 6, j = idx & 63;
    float s = 0.0f;
    #pragma unroll 8
    for (int k = 0; k < 64; ++k)
      s = fmaf(ew2s[i * 64 + k], nw1s[k * 64 + j], s);
    mv[p] = s;
  }
  if (t < 64) {
    float s = 0.0f;
    #pragma unroll 8
    for (int k = 0; k < 64; ++k)
      s = fmaf(ws[OFF_EB2 + k], nw1s[k * 64 + t], s);
    ws[OFF_V + t] = s;
  }
  __syncthreads();
  #pragma unroll
  for (int p = 0; p < 4; ++p) ew2s[t + p * 1024] = mv[p];   // M now lives in ew2s
  __syncthreads();

  if (t < 64) {
    unsigned short* w1t = (unsigned short*)(ws + OFF_W1T);
    #pragma unroll
    for (int k = 0; k < 8; ++k) {
      float v = 0.0f;
      if (k < 5) v = ws[OFF_EW1 + k * 64 + t];
      else if (k == 5) v = ws[OFF_EB1 + t];
      w1t[t * 8 + k] = f2bu(v);
    }
  }
  unsigned short* mt = (unsigned short*)(ws + OFF_MT);
  #pragma unroll
  for (int p = 0; p < 4; ++p) {
    const int idx = t + p * 1024;
    const int n = idx >> 6, k = idx & 63;
    mt[idx] = f2bu(ew2s[k * 64 + n]);
  }
}

// ---------------------------------------------------------------------------
// count (+ merged bounds): per-block LDS histogram over COARSE GROUPS.
// r20-verified: pair-vectorized edge loads.
// ---------------------------------------------------------------------------
template<typename IT>
__device__ __forceinline__ void count_impl(
    const IT* __restrict__ ei, const IT* __restrict__ bt,
    int* __restrict__ gcnt, int* __restrict__ endG, int* lh,
    const int E, const int N, const int NBG)
{
  const int t = threadIdx.x;
  const int b = blockIdx.x;
  for (int i = t; i < NBG; i += NCT) lh[i] = 0;
  {
    const int i = b * NCT + t;            // merged bounds pass
    if (i < N) {
      const int g1 = (int)bt[i];
      if (i == 0) for (int g = 0; g < g1; ++g) endG[g] = 0;
      if (i == N - 1) {
        for (int g = g1; g < NGRAPH; ++g) endG[g] = N;
      } else {
        const int g2 = (int)bt[i + 1];
        for (int g = g1; g < g2; ++g) endG[g] = i + 1;
      }
    }
  }
  __syncthreads();
  const int per = (E + NCB - 1) / NCB;
  const int a = b * per;
  const int bnd = (a + per < E) ? (a + per) : E;
  const IT* col = ei + E;
  if ((E & 1) == 0) {                       // vector path (16B-aligned pairs)
    const int pa = (a + 1) >> 1;
    const int pb = bnd >> 1;
    if ((a & 1) && a < bnd && t == 0)
      atomicAdd(&lh[(int)col[a] >> 8], 1);
    if ((bnd & 1) && bnd - 1 >= a && t == NCT - 1)
      atomicAdd(&lh[(int)col[bnd - 1] >> 8], 1);
    for (int p = pa + t; p < pb; p += NCT) {
      int c0, c1;
      if constexpr (sizeof(IT) == 8) {
        const int4 v = ((const int4*)col)[p];
        c0 = v.x; c1 = v.z;
      } else {
        const int2 v = ((const int2*)col)[p];
        c0 = v.x; c1 = v.y;
      }
      atomicAdd(&lh[c0 >> 8], 1);
      atomicAdd(&lh[c1 >> 8], 1);
    }
  } else {
    for (int e = a + t; e < bnd; e += NCT)
      atomicAdd(&lh[(int)col[e] >> 8], 1);
  }
  __syncthreads();
  for (int i = t; i < NBG; i += NCT) gcnt[(size_t)i * NCB + b] = lh[i];
}

__global__ __launch_bounds__(NCT) void count_kernel(
    const void* eiv, const void* batv, const float* ws,
    int* gcnt, int* endG, const int E, const int N, const int NBG)
{
  __shared__ int lh[MAXNB];
  const int it = ((const int*)(ws + OFF_FLAGS))[1];
  if (it) count_impl<long long>((const long long*)eiv, (const long long*)batv, gcnt, endG, lh, E, N, NBG);
  else    count_impl<int>((const int*)eiv, (const int*)batv, gcnt, endG, lh, E, N, NBG);
}

// ---------------------------------------------------------------------------
// scan (r21: single-kernel, 1 block x 1024 threads; replaces the 3-kernel
// chain -- same arithmetic: row totals -> exclusive prefix -> row rewrite).
// ---------------------------------------------------------------------------
__global__ __launch_bounds__(1024) void scan_kernel(
    int* __restrict__ gcnt, int* __restrict__ gstart, const int NBG)
{
  __shared__ int tot[257];
  const int t = threadIdx.x;
  const int lane = t & 63;
  const int wav = t >> 6;

  // phase 1: row totals
  for (int r = wav; r < NBG; r += 16) {
    const int4 v = *(const int4*)(gcnt + (size_t)r * NCB + lane * 4);
    int s = v.x + v.y + v.z + v.w;
    #pragma unroll
    for (int o = 32; o > 0; o >>= 1) s += __shfl_xor(s, o);
    if (lane == 0) tot[r] = s;
  }
  __syncthreads();

  // phase 2: exclusive prefix over tot[0..NBG) (wave 0; 4 rows per lane)
  if (wav == 0) {
    const int b0 = lane * 4;
    int v0 = (b0 + 0 < NBG) ? tot[b0 + 0] : 0;
    int v1 = (b0 + 1 < NBG) ? tot[b0 + 1] : 0;
    int v2 = (b0 + 2 < NBG) ? tot[b0 + 2] : 0;
    int v3 = (b0 + 3 < NBG) ? tot[b0 + 3] : 0;
    const int ls = v0 + v1 + v2 + v3;
    int s = ls;
    #pragma unroll
    for (int o = 1; o < 64; o <<= 1) {
      const int u = __shfl_up(s, o);
      if (lane >= o) s += u;
    }
    int e = s - ls;
    if (b0 + 0 < NBG) { gstart[b0 + 0] = e; tot[b0 + 0] = e; e += v0; }
    if (b0 + 1 < NBG) { gstart[b0 + 1] = e; tot[b0 + 1] = e; e += v1; }
    if (b0 + 2 < NBG) { gstart[b0 + 2] = e; tot[b0 + 2] = e; e += v2; }
    if (b0 + 3 < NBG) { gstart[b0 + 3] = e; tot[b0 + 3] = e; e += v3; }
    if (lane == 63) gstart[NBG] = s;   // grand total (pads are zero)
  }
  __syncthreads();

  // phase 3: rewrite rows as absolute positions
  for (int r = wav; r < NBG; r += 16) {
    int* row = gcnt + (size_t)r * NCB;
    const int4 v = *(const int4*)(row + lane * 4);
    const int ls = v.x + v.y + v.z + v.w;
    int s = ls;
    #pragma unroll
    for (int o = 1; o < 64; o <<= 1) {
      const int u = __shfl_up(s, o);
      if (lane >= o) s += u;
    }
    int e = s - ls + tot[r];
    int4 o4;
    o4.x = e; e += v.x;
    o4.y = e; e += v.y;
    o4.z = e; e += v.z;
    o4.w = e;
    *(int4*)(row + lane * 4) = o4;
  }
}

// ---------------------------------------------------------------------------
// scatter pass 1 (r20-verified): bf16 fast path processes edge PAIRS.
// ---------------------------------------------------------------------------
template<typename FT, typename IT>
__device__ __forceinline__ void scat_one(
    const FT* __restrict__ x, const IT* __restrict__ ei, const FT* __restrict__ ea,
    int* lb, ushort4* __restrict__ recB, unsigned char* __restrict__ cid,
    const int E, const int e, const int gb0, const int gb1, const int cap)
{
  const int c = (int)ei[(size_t)E + e];
  const int grp = c >> 8;
  if (grp >= gb0 && grp < gb1) {
    const int pos = atomicAdd(&lb[grp - gb0], 1);
    if (pos < cap) {
      const int r = (int)ei[e];
      ushort4 rv;
      rv.x = fr(cv(x[r]));
      rv.y = fr(cv(ea[(size_t)3 * e + 0]));
      rv.z = fr(cv(ea[(size_t)3 * e + 1]));
      rv.w = fr(cv(ea[(size_t)3 * e + 2]));
      recB[pos] = rv;
      cid[pos] = (unsigned char)(c & 255);
    }
  }
}

template<typename FT, typename IT>
__device__ __forceinline__ void scatter_impl(
    const FT* __restrict__ x, const IT* __restrict__ ei, const FT* __restrict__ ea,
    const int* __restrict__ gcnt, const int* __restrict__ gstart,
    ushort4* __restrict__ recB, unsigned char* __restrict__ cid, int* lb,
    const int E, const int gb0, const int gb1, const int cap)
{
  const int t = threadIdx.x;
  const int b = blockIdx.x;
  __shared__ int sbase;
  if (t == 0) sbase = gstart[gb0];
  __syncthreads();
  const int base = sbase;
  const int gcount = gb1 - gb0;
  for (int i = t; i < gcount; i += NCT) lb[i] = gcnt[(size_t)(gb0 + i) * NCB + b] - base;
  __syncthreads();

  const int per = (E + NCB - 1) / NCB;
  const int a = b * per;
  const int bnd = (a + per < E) ? (a + per) : E;
  for (int e = a + t; e < bnd; e += NCT)
    scat_one<FT, IT>(x, ei, ea, lb, recB, cid, E, e, gb0, gb1, cap);
}

// bf16 + even-E fast path: edge pairs, vector loads, raw bit payload copy.
template<typename IT>
__device__ __forceinline__ void scatter_fast(
    const unsigned short* __restrict__ x, const IT* __restrict__ ei,
    const void* __restrict__ eav,
    const int* __restrict__ gcnt, const int* __restrict__ gstart,
    ushort4* __restrict__ recB, unsigned char* __restrict__ cid, int* lb,
    const int E, const int gb0, const int gb1, const int cap)
{
  const int t = threadIdx.x;
  const int b = blockIdx.x;
  __shared__ int sbase2;
  if (t == 0) sbase2 = gstart[gb0];
  __syncthreads();
  const int base = sbase2;
  const int gcount = gb1 - gb0;
  for (int i = t; i < gcount; i += NCT) lb[i] = gcnt[(size_t)(gb0 + i) * NCB + b] - base;
  __syncthreads();

  const int per = (E + NCB - 1) / NCB;
  const int a = b * per;
  const int bnd = (a + per < E) ? (a + per) : E;
  const int pa = (a + 1) >> 1;
  const int pb = bnd >> 1;

  // head/tail odd edges via scalar helper (bf16 view)
  const __hip_bfloat16* xb = (const __hip_bfloat16*)x;
  const __hip_bfloat16* eab = (const __hip_bfloat16*)eav;
  if ((a & 1) && a < bnd && t == 0)
    scat_one<__hip_bfloat16, IT>(xb, ei, eab, lb, recB, cid, E, a, gb0, gb1, cap);
  if ((bnd & 1) && bnd - 1 >= a && t == NCT - 1)
    scat_one<__hip_bfloat16, IT>(xb, ei, eab, lb, recB, cid, E, bnd - 1, gb0, gb1, cap);

  const IT* col = ei + E;
  for (int p = pa + t; p < pb; p += NCT) {
    int c0, c1, r0, r1;
    if constexpr (sizeof(IT) == 8) {
      const int4 vc = ((const int4*)col)[p];
      c0 = vc.x; c1 = vc.z;
      const int4 vr = ((const int4*)ei)[p];
      r0 = vr.x; r1 = vr.z;
    } else {
      const int2 vc = ((const int2*)col)[p];
      c0 = vc.x; c1 = vc.y;
      const int2 vr = ((const int2*)ei)[p];
      r0 = vr.x; r1 = vr.y;
    }
    const uint3 d = ((const uint3*)eav)[p];   // 12B = both edges' 3 bf16 attrs

    const int g0 = c0 >> 8;
    if (g0 >= gb0 && g0 < gb1) {
      const int pos = atomicAdd(&lb[g0 - gb0], 1);
      if (pos < cap) {
        ushort4 rv;
        rv.x = x[r0];
        rv.y = (unsigned short)(d.x & 0xFFFFu);
        rv.z = (unsigned short)(d.x >> 16);
        rv.w = (unsigned short)(d.y & 0xFFFFu);
        recB[pos] = rv;
        cid[pos] = (unsigned char)(c0 & 255);
      }
    }
    const int g1 = c1 >> 8;
    if (g1 >= gb0 && g1 < gb1) {
      const int pos = atomicAdd(&lb[g1 - gb0], 1);
      if (pos < cap) {
        ushort4 rv;
        rv.x = x[r1];
        rv.y = (unsigned short)(d.y >> 16);
        rv.z = (unsigned short)(d.z & 0xFFFFu);
        rv.w = (unsigned short)(d.z >> 16);
        recB[pos] = rv;
        cid[pos] = (unsigned char)(c1 & 255);
      }
    }
  }
}

__global__ __launch_bounds__(NCT) void scatter_kernel(
    const void* xv, const void* eiv, const void* eav, const float* ws,
    const int* gcnt, const int* gstart, ushort4* recB, unsigned char* cid,
    const int E, const int gb0, const int gb1, const int cap)
{
  __shared__ int lb[MAXNB];
  const int* fl = (const int*)(ws + OFF_FLAGS);
  const int ft = fl[0], it = fl[1];
  if (ft && ((E & 1) == 0)) {
    if (it) scatter_fast<long long>((const unsigned short*)xv, (const long long*)eiv, eav, gcnt, gstart, recB, cid, lb, E, gb0, gb1, cap);
    else    scatter_fast<int>((const unsigned short*)xv, (const int*)eiv, eav, gcnt, gstart, recB, cid, lb, E, gb0, gb1, cap);
  } else if (ft) {
    if (it) scatter_impl<__hip_bfloat16, long long>((const __hip_bfloat16*)xv, (const long long*)eiv, (const __hip_bfloat16*)eav, gcnt, gstart, recB, cid, lb, E, gb0, gb1, cap);
    else    scatter_impl<__hip_bfloat16, int>((const __hip_bfloat16*)xv, (const int*)eiv, (const __hip_bfloat16*)eav, gcnt, gstart, recB, cid, lb, E, gb0, gb1, cap);
  } else {
    if (it) scatter_impl<float, long long>((const float*)xv, (const long long*)eiv, (const float*)eav, gcnt, gstart, recB, cid, lb, E, gb0, gb1, cap);
    else    scatter_impl<float, int>((const float*)xv, (const int*)eiv, (const float*)eav, gcnt, gstart, recB, cid, lb, E, gb0, gb1, cap);
  }
}

// ---------------------------------------------------------------------------
// sort pass 2: one block per coarse group; LDS-staged in-place fine sort.
// ---------------------------------------------------------------------------
__global__ __launch_bounds__(SORT_T) void sort_kernel(
    ushort4* __restrict__ recB, unsigned char* __restrict__ cid,
    const int* __restrict__ gstart, int* __restrict__ bstartF,
    const int NB, const int gr0, const int cap)
{
  __shared__ unsigned sru[SORT_CHUNK * 2];     // 102.4 KB record payload
  __shared__ unsigned char sc[SORT_CHUNK];     // 12.8 KB keys
  __shared__ int h2[16][GB];                   // per-wave histograms
  __shared__ int fs[GB];
  __shared__ int cur[GB];

  const int t = threadIdx.x;
  const int lane = t & 63;
  const int wav = t >> 6;
  const int g = gr0 + (int)blockIdx.x;

  const int base0 = gstart[gr0];
  int rb = gstart[g] - base0;
  int re = gstart[g + 1] - base0;
  if (rb > cap) rb = cap;
  if (re > cap) re = cap;
  int cnt = re - rb;
  if (cnt > SORT_CHUNK) cnt = SORT_CHUNK;

  if (t < 16 * GB) ((int*)h2)[t] = 0;
  __syncthreads();

  // stage to LDS + per-wave histogram (ballot-aggregated, no atomics)
  for (int i = t; i < cnt; i += SORT_T) {
    const ushort4 r = recB[rb + i];
    sru[2 * i]     = (unsigned)r.x | ((unsigned)r.y << 16);
    sru[2 * i + 1] = (unsigned)r.z | ((unsigned)r.w << 16);
    const unsigned char c = cid[rb + i];
    sc[i] = c;
    const int kk = c >> 5;
    unsigned long long mym = 0;
    #pragma unroll
    for (int k = 0; k < GB; ++k) {
      const unsigned long long bk = __ballot(kk == k);
      if (kk == k) mym = bk;
    }
    if ((mym & (((unsigned long long)1 << lane) - 1ull)) == 0)   // leader per key
      h2[wav][kk] += (int)__builtin_popcountll(mym);
  }
  __syncthreads();

  if (t == 0) {
    int acc = 0;
    for (int k = 0; k < GB; ++k) {
      int s = 0;
      #pragma unroll
      for (int w = 0; w < 16; ++w) s += h2[w][k];
      fs[k] = acc;
      cur[k] = acc;
      acc += s;
    }
  }
  __syncthreads();

  // fine bucket starts (absolute)
  if (t <= GB) {
    const int bk = g * GB + t;
    if (bk <= NB) bstartF[bk] = base0 + rb + ((t == GB) ? cnt : fs[t]);
  }

  // in-place scatter to final bucket-sorted positions
  for (int i = t; i < cnt; i += SORT_T) {
    const unsigned char c = sc[i];
    const int kk = c >> 5;
    unsigned long long mym = 0;
    #pragma unroll
    for (int k = 0; k < GB; ++k) {
      const unsigned long long bk = __ballot(kk == k);
      if (kk == k) mym = bk;
    }
    const int lead = (int)__builtin_ctzll(mym);
    const int off = (int)__builtin_popcountll(mym & (((unsigned long long)1 << lane) - 1ull));
    int bas = 0;
    if (lane == lead) bas = atomicAdd(&cur[kk], (int)__builtin_popcountll(mym));
    bas = __shfl(bas, lead);
    const int pos = rb + bas + off;
    const unsigned a = sru[2 * i], b = sru[2 * i + 1];
    ushort4 rv;
    rv.x = (unsigned short)(a & 0xFFFFu); rv.y = (unsigned short)(a >> 16);
    rv.z = (unsigned short)(b & 0xFFFFu); rv.w = (unsigned short)(b >> 16);
    recB[pos] = rv;
    cid[pos] = (unsigned char)(c & 31);
  }
}

// ---------------------------------------------------------------------------
// fused (cooperative MFMA, r19-verified structure): pair-phase schedule,
// incremental one-hot, reg-held A1, scalar prefetch.
// r21: H->bf16 conversion via v_cvt_pk_bf16_f32 (was rndpack, ~40% of VALU).
// ---------------------------------------------------------------------------

#define FUSED_H(J, RV, CC)                                                       \
    if ((J) < jmax) {                                                            \
      short* HT = sHT + ((J) & 1) * 4608;                                        \
      short8 a1;                                                                 \
      if (quad == 0) {                                                           \
        const bool vv = (CC) < 32;                                               \
        a1[0] = (short)(RV).x;                                                   \
        a1[1] = vv ? (short)xlsb[(CC)] : (short)0;                               \
        a1[2] = (short)(RV).y; a1[3] = (short)(RV).z; a1[4] = (short)(RV).w;     \
        a1[5] = vv ? (short)0x3F80 : (short)0;                                   \
        a1[6] = 0; a1[7] = 0;                                                    \
      } else {                                                                   \
        a1[0]=0; a1[1]=0; a1[2]=0; a1[3]=0; a1[4]=0; a1[5]=0; a1[6]=0; a1[7]=0;  \
      }                                                                          \
      f32x4 Hc0 = __builtin_amdgcn_mfma_f32_16x16x32_bf16(a1, B1[0], (f32x4)0.0f, 0, 0, 0); \
      f32x4 Hc1 = __builtin_amdgcn_mfma_f32_16x16x32_bf16(a1, B1[1], (f32x4)0.0f, 0, 0, 0); \
      f32x4 Hc2 = __builtin_amdgcn_mfma_f32_16x16x32_bf16(a1, B1[2], (f32x4)0.0f, 0, 0, 0); \
      f32x4 Hc3 = __builtin_amdgcn_mfma_f32_16x16x32_bf16(a1, B1[3], (f32x4)0.0f, 0, 0, 0); \
      uint2 pk0, pk1, pk2, pk3;                                                  \
      pk0.x = cvtpk(Hc0[0], Hc0[1]); pk0.y = cvtpk(Hc0[2], Hc0[3]);              \
      pk1.x = cvtpk(Hc1[0], Hc1[1]); pk1.y = cvtpk(Hc1[2], Hc1[3]);              \
      pk2.x = cvtpk(Hc2[0], Hc2[1]); pk2.y = cvtpk(Hc2[2], Hc2[3]);              \
      pk3.x = cvtpk(Hc3[0], Hc3[1]); pk3.y = cvtpk(Hc3[2], Hc3[3]);              \
      *(uint2*)(HT + ( 0 + l15) * 72 + 16 * wav + quad * 4) = pk0;               \
      *(uint2*)(HT + (16 + l15) * 72 + 16 * wav + quad * 4) = pk1;               \
      *(uint2*)(HT + (32 + l15) * 72 + 16 * wav + quad * 4) = pk2;               \
      *(uint2*)(HT + (48 + l15) * 72 + 16 * wav + quad * 4) = pk3;               \
    }

#define FUSED_PV(J)                                                             \
    if ((J) < jmax) {                                                           \
      const short* HT = sHT + ((J) & 1) * 4608;                                 \
      const short* aj = a2L + (J) * 2304;                                       \
      _Pragma("unroll")                                                         \
      for (int q = 0; q < 2; ++q) {                                             \
        const short8 a20 = *(const short8*)(aj + l15 * 72 + 32 * q + 8 * quad); \
        const short8 a21 = *(const short8*)(aj + (16 + l15) * 72 + 32 * q + 8 * quad); \
        const short8 b2  = *(const short8*)(HT + (16 * wav + l15) * 72 + 32 * q + quad * 8); \
        C2[0] = __builtin_amdgcn_mfma_f32_16x16x32_bf16(a20, b2, C2[0], 0, 0, 0);\
        C2[1] = __builtin_amdgcn_mfma_f32_16x16x32_bf16(a21, b2, C2[1], 0, 0, 0);\
        C3[0] = __builtin_amdgcn_mfma_f32_16x16x32_bf16(a20, ONES8, C3[0], 0, 0, 0); \
        C3[1] = __builtin_amdgcn_mfma_f32_16x16x32_bf16(a21, ONES8, C3[1], 0, 0, 0); \
      }                                                                         \
    }

template<typename FT, typename IT>
__device__ __forceinline__ void fused_impl(
    const FT* __restrict__ x, const IT* __restrict__ batch,
    const float* __restrict__ ws, const int* __restrict__ bstart,
    const ushort4* __restrict__ recB, const unsigned char* __restrict__ cid,
    float* __restrict__ rep,
    short* sHT, short* a2L,
    float* xls, unsigned short* xlsb, int* sbi,
    const int N, const int gb0, const int cap)
{
  const int t = threadIdx.x;
  const int lane = t & 63;
  const int quad = lane >> 4;
  const int l15 = lane & 15;
  const int wav = t >> 6;
  const int bucket = gb0 + blockIdx.x;

  // initial full zero of a2L (once; afterwards incrementally maintained)
  {
    unsigned long long* az = (unsigned long long*)a2L;
    #pragma unroll
    for (int z = 0; z < 9; ++z) az[t + z * 256] = 0ull;
  }
  if (t < BN) {
    const int n = bucket * BN + t;
    const float xvv = (n < N) ? cv(x[n]) : 0.0f;
    xls[t] = xvv;
    xlsb[t] = fr(xvv);
  }
  if (t == 0) {
    const int nf = bucket * BN, nl = bucket * BN + BN - 1;
    sbi[0] = (int)batch[(nf < N) ? nf : (N - 1)];
    sbi[1] = (int)batch[(nl < N) ? nl : (N - 1)];
    sbi[2] = bstart[gb0];
  }
  __syncthreads();

  const unsigned short* w1t = (const unsigned short*)(ws + OFF_W1T);
  short8 B1[4];
  #pragma unroll
  for (int tn = 0; tn < 4; ++tn) {
    short8 z; for (int j = 0; j < 8; ++j) z[j] = 0;
    if (quad == 0) z = *(const short8*)(w1t + (16 * tn + l15) * 8);
    B1[tn] = z;
  }
  short8 ONES8;
  #pragma unroll
  for (int j = 0; j < 8; ++j) ONES8[j] = (short)0x3F80;

  const int base = sbi[2];
  int s0 = bstart[bucket] - base;
  int e0 = bstart[bucket + 1] - base;
  if (s0 > cap) s0 = cap;
  if (e0 > cap) e0 = cap;

  f32x4 C2[2]; C2[0] = (f32x4)0.0f; C2[1] = (f32x4)0.0f;
  f32x4 C3[2]; C3[0] = (f32x4)0.0f; C3[1] = (f32x4)0.0f;

  const int nedge = e0 - s0;
  const int nst = (nedge + 255) >> 8;

  // quad-0 lane (wav,l15) owns edges 64*j + 16*wav + l15 of each stage.
  const ushort4 uz = make_ushort4(0, 0, 0, 0);
  ushort4 rv0 = uz, rv1 = uz, rv2 = uz, rv3 = uz;
  int c0 = 255, c1 = 255, c2 = 255, c3 = 255;
  int cp0 = 255, cp1 = 255, cp2 = 255, cp3 = 255;   // previously-set one-hot col
  if (nst > 0 && quad == 0) {
    int idx;
    idx = s0 +   0 + 16 * wav + l15; if (idx < e0) { rv0 = recB[idx]; c0 = (int)cid[idx]; }
    idx = s0 +  64 + 16 * wav + l15; if (idx < e0) { rv1 = recB[idx]; c1 = (int)cid[idx]; }
    idx = s0 + 128 + 16 * wav + l15; if (idx < e0) { rv2 = recB[idx]; c2 = (int)cid[idx]; }
    idx = s0 + 192 + 16 * wav + l15; if (idx < e0) { rv3 = recB[idx]; c3 = (int)cid[idx]; }
  }

  for (int st = 0; st < nst; ++st) {
    const int m = nedge - st * 256;
    const int jmax = (m >= 256) ? 4 : ((m + 63) >> 6);

    // incremental one-hot update (same-thread slot ownership)
    if (quad == 0) {
      const int row = 16 * wav + l15;
      if (cp0 != c0) { if (cp0 < 32) a2L[0 * 2304 + cp0 * 72 + row] = 0;
                       if (c0  < 32) a2L[0 * 2304 + c0  * 72 + row] = (short)0x3F80; }
      if (cp1 != c1) { if (cp1 < 32) a2L[1 * 2304 + cp1 * 72 + row] = 0;
                       if (c1  < 32) a2L[1 * 2304 + c1  * 72 + row] = (short)0x3F80; }
      if (cp2 != c2) { if (cp2 < 32) a2L[2 * 2304 + cp2 * 72 + row] = 0;
                       if (c2  < 32) a2L[2 * 2304 + c2  * 72 + row] = (short)0x3F80; }
      if (cp3 != c3) { if (cp3 < 32) a2L[3 * 2304 + cp3 * 72 + row] = 0;
                       if (c3  < 32) a2L[3 * 2304 + c3  * 72 + row] = (short)0x3F80; }
    }
    cp0 = c0; cp1 = c1; cp2 = c2; cp3 = c3;

    // prefetch next stage into scalar regs; HBM latency hides under MFMA
    ushort4 nv0 = uz, nv1 = uz, nv2 = uz, nv3 = uz;
    int n0 = 255, n1 = 255, n2 = 255, n3 = 255;
    if (st + 1 < nst && quad == 0) {
      const int nb = s0 + (st + 1) * 256 + 16 * wav + l15;
      int idx;
      idx = nb;       if (idx < e0) { nv0 = recB[idx]; n0 = (int)cid[idx]; }
      idx = nb +  64; if (idx < e0) { nv1 = recB[idx]; n1 = (int)cid[idx]; }
      idx = nb + 128; if (idx < e0) { nv2 = recB[idx]; n2 = (int)cid[idx]; }
      idx = nb + 192; if (idx < e0) { nv3 = recB[idx]; n3 = (int)cid[idx]; }
    }

    FUSED_H(0, rv0, c0)
    FUSED_H(1, rv1, c1)
    __syncthreads();
    FUSED_PV(0)
    FUSED_PV(1)
    __syncthreads();
    if (jmax > 2) {
      FUSED_H(2, rv2, c2)
      FUSED_H(3, rv3, c3)
      __syncthreads();
      FUSED_PV(2)
      FUSED_PV(3)
      __syncthreads();
    }
    rv0 = nv0; c0 = n0; rv1 = nv1; c1 = n1;
    rv2 = nv2; c2 = n2; rv3 = nv3; c3 = n3;
  }

  short* aggB = a2L;   // overlay rows 0..31 (4608B); a2L dead after main loop
  #pragma unroll
  for (int tm2 = 0; tm2 < 2; ++tm2) {
    #pragma unroll
    for (int r = 0; r < 4; ++r)
      aggB[(16 * tm2 + quad * 4 + r) * 72 + 16 * wav + l15] = (short)fr(C2[tm2][r]);
  }
  __syncthreads();

  const unsigned short* mt = (const unsigned short*)(ws + OFF_MT);
  f32x4 D[2]; D[0] = (f32x4)0.0f; D[1] = (f32x4)0.0f;
  #pragma unroll
  for (int q2 = 0; q2 < 2; ++q2) {
    const short8 bb = *(const short8*)(mt + (16 * wav + l15) * 64 + 32 * q2 + quad * 8);
    #pragma unroll
    for (int tm2 = 0; tm2 < 2; ++tm2) {
      const short8 aa = *(const short8*)(aggB + (16 * tm2 + l15) * 72 + 32 * q2 + quad * 8);
      D[tm2] = __builtin_amdgcn_mfma_f32_16x16x32_bf16(aa, bb, D[tm2], 0, 0, 0);
    }
  }

  const int n = 16 * wav + l15;
  const float c1n = ws[OFF_NW1 + n];
  const float vn  = ws[OFF_V + n];
  const float bn  = ws[OFF_NB1 + n];
  float* myrep = rep + (size_t)(bucket & 7) * (NGRAPH * 64);
  const bool multi = (sbi[0] != sbi[1]);

  if (!multi) {
    // fast path: whole bucket in one graph -> quad-reduce + 1 atomic per (g,n)
    float hs = 0.0f;
    #pragma unroll
    for (int tm2 = 0; tm2 < 2; ++tm2) {
      #pragma unroll
      for (int r = 0; r < 4; ++r) {
        const int mrow = 16 * tm2 + quad * 4 + r;
        const int ng = bucket * BN + mrow;
        if (ng < N)
          hs += fmaxf(D[tm2][r] + xls[mrow] * c1n + C3[tm2][r] * vn + bn, 0.0f);
      }
    }
    hs += __shfl_xor(hs, 16);
    hs += __shfl_xor(hs, 32);
    if (quad == 0) unsafeAtomicAdd(&myrep[sbi[0] * 64 + n], hs);
  } else {
    float* pooledL = (float*)((char*)a2L + 4608);   // behind aggB rows, 4096B
    for (int i = t; i < NGRAPH * 64; i += 256) pooledL[i] = 0.0f;
    __syncthreads();
    #pragma unroll
    for (int tm2 = 0; tm2 < 2; ++tm2) {
      #pragma unroll
      for (int r = 0; r < 4; ++r) {
        const int mrow = 16 * tm2 + quad * 4 + r;
        const int ng = bucket * BN + mrow;
        if (ng < N) {
          const float h = fmaxf(D[tm2][r] + xls[mrow] * c1n + C3[tm2][r] * vn + bn, 0.0f);
          const int g = (int)batch[ng];
          atomicAdd(&pooledL[g * 64 + n], h);
        }
      }
    }
    __syncthreads();
    for (int g = sbi[0] + wav; g <= sbi[1]; g += 4)
      unsafeAtomicAdd(&myrep[g * 64 + lane], pooledL[g * 64 + lane]);
  }
}

__global__ __launch_bounds__(256, 4) void fused_kernel(
    const void* xv, const void* batv, const float* ws, const int* bstart,
    const ushort4* recB, const unsigned char* cid, float* rep,
    const int N, const int gb0, const int cap)
{
  // carved LDS (37.1 KB -> 4 blocks/CU): sHT dbuf 18432 | a2L/aggB/pooledL 18432 | misc
  __shared__ __align__(16) unsigned char smem[37072];
  short* sHT = (short*)smem;
  short* a2L = (short*)(smem + 18432);
  float* xls = (float*)(smem + 36864);
  unsigned short* xlsb = (unsigned short*)(smem + 36992);
  int* sbi = (int*)(smem + 37056);

  const int* fl = (const int*)(ws + OFF_FLAGS);
  const int ft = fl[0], it = fl[1];
  if (ft) {
    if (it) fused_impl<__hip_bfloat16, long long>((const __hip_bfloat16*)xv, (const long long*)batv, ws, bstart, recB, cid, rep, sHT, a2L, xls, xlsb, sbi, N, gb0, cap);
    else    fused_impl<__hip_bfloat16, int>((const __hip_bfloat16*)xv, (const int*)batv, ws, bstart, recB, cid, rep, sHT, a2L, xls, xlsb, sbi, N, gb0, cap);
  } else {
    if (it) fused_impl<float, long long>((const float*)xv, (const long long*)batv, ws, bstart, recB, cid, rep, sHT, a2L, xls, xlsb, sbi, N, gb0, cap);
    else    fused_impl<float, int>((const float*)xv, (const int*)batv, ws, bstart, recB, cid, rep, sHT, a2L, xls, xlsb, sbi, N, gb0, cap);
  }
}

// ---------------------------------------------------------------------------
// head: reduce 8 pooled replicas; cnt from precomputed endG; dense head.
// ---------------------------------------------------------------------------
__global__ __launch_bounds__(256) void head_kernel(
    const float* ws, const float* rep, const int* __restrict__ endG,
    void* outv, const int N)
{
  __shared__ float P[NGRAPH][HID];
  __shared__ float A[NGRAPH][HID];
  __shared__ float B[NGRAPH][HID];
  __shared__ int endL[NGRAPH];

  const int t = threadIdx.x;
  const int j = t & 63;
  const int gq = t >> 6;

  if (t < NGRAPH) endL[t] = endG[t];

  #pragma unroll
  for (int gi = 0; gi < 4; ++gi) {
    const int g = gq + gi * 4;
    float s = 0.0f;
    #pragma unroll
    for (int r = 0; r < 8; ++r)
      s += rep[(size_t)r * (NGRAPH * 64) + g * 64 + j];
    P[g][j] = s;
  }
  __syncthreads();

  {
    const float bj = ws[OFF_NB2 + j];
    #pragma unroll
    for (int gi = 0; gi < 4; ++gi) {
      const int g = gq + gi * 4;
      const float cg = (float)(endL[g] - (g ? endL[g - 1] : 0));
      float s = cg * bj;
      #pragma unroll 8
      for (int k = 0; k < HID; ++k)
        s = fmaf(P[g][k], ws[OFF_NW2 + k * HID + j], s);
      A[g][j] = s;
    }
  }
  __syncthreads();

  const int wOff[3] = {OFF_OW1, OFF_OW2, OFF_OW3};
  const int bOff[3] = {OFF_OB1, OFF_OB2, OFF_OB3};
  for (int L = 0; L < 3; ++L) {
    float (*In)[HID]  = (L & 1) ? B : A;
    float (*Out)[HID] = (L & 1) ? A : B;
    const float bj = ws[bOff[L] + j];
    #pragma unroll
    for (int gi = 0; gi < 4; ++gi) {
      const int g = gq + gi * 4;
      float s = bj;
      #pragma unroll 8
      for (int k = 0; k < HID; ++k)
        s = fmaf(In[g][k], ws[wOff[L] + k * HID + j], s);
      Out[g][j] = fmaxf(s, 0.0f);
    }
    __syncthreads();
  }

  if (t < 32) {
    const int g = t >> 1, d = t & 1;
    float s = ws[OFF_OB4 + d];
    #pragma unroll 8
    for (int k = 0; k < HID; ++k)
      s = fmaf(B[g][k], ws[OFF_OW4 + k * 2 + d], s);
    const int ft = ((const int*)(ws + OFF_FLAGS))[0];
    if (ft) ((__hip_bfloat16*)outv)[g * 2 + d] = __float2bfloat16(s);
    else    ((float*)outv)[g * 2 + d] = s;
  }
}

extern "C" void kernel_launch(void* const* d_in, const int* in_sizes, int n_in,
                              void* d_out, int out_size, void* d_ws, size_t ws_size,
                              hipStream_t stream)
{
  const void* xv   = d_in[0];
  const void* eiv  = d_in[1];
  const void* eav  = d_in[2];
  const void* batv = d_in[3];

  WPtrs wp;
  for (int a = 0; a < 16; ++a) wp.p[a] = d_in[4 + a];

  const int N = in_sizes[0];
  const int E = in_sizes[1] / 2;
  const int NB = (N + BN - 1) / BN;
  const int NBG = (NB + GB - 1) / GB;
  if (NB > MAXNB) return;

  float* ws    = (float*)d_ws;
  float* rep   = ws + OFF_PREP;                            // 8*1024 floats
  int* gstart  = (int*)(rep + 8 * NGRAPH * 64);            // NBG+1 ints
  int* bstartF = gstart + NBG + 1;                         // NB+2 ints
  int* endG    = bstartF + NB + 2;                         // 16 ints
  int* gcnt    = endG + NGRAPH;                            // NBG*NCB ints

  size_t recOffB = ((size_t)((char*)(gcnt + (size_t)NBG * NCB) - (char*)d_ws) + 15) & ~(size_t)15;

  int G = -1; long long cap = 0;
  for (int g = 1; g <= 64; ++g) {
    const long long c = (long long)E / g + E / 32 + 8192;
    if (recOffB + (size_t)c * 9 <= ws_size) { G = g; cap = c; break; }
  }
  if (G < 0) return;

  ushort4* recB = (ushort4*)((char*)d_ws + recOffB);
  unsigned char* cid = (unsigned char*)(recB + cap);
  const int gsz = (NBG + G - 1) / G;

  (void)hipMemsetAsync(rep, 0, (size_t)(8 * NGRAPH * 64) * 4, stream);

  prep_kernel<<<1, 1024, 0, stream>>>(xv, eiv, wp, ws);
  count_kernel<<<NCB, NCT, 0, stream>>>(eiv, batv, ws, gcnt, endG, E, N, NBG);
  scan_kernel<<<1, 1024, 0, stream>>>(gcnt, gstart, NBG);

  for (int g = 0; g < G; ++g) {
    const int gr0 = g * gsz;
    const int gr1 = (gr0 + gsz < NBG) ? (gr0 + gsz) : NBG;
    if (gr0 >= gr1) break;
    scatter_kernel<<<NCB, NCT, 0, stream>>>(xv, eiv, eav, ws, gcnt, gstart,
                                            recB, cid, E, gr0, gr1, (int)cap);
    sort_kernel<<<gr1 - gr0, SORT_T, 0, stream>>>(recB, cid, gstart, bstartF,
                                                  NB, gr0, (int)cap);
    const int b0 = gr0 * GB;
    const int b1 = (gr1 * GB < NB) ? (gr1 * GB) : NB;
    fused_kernel<<<b1 - b0, 256, 0, stream>>>(xv, batv, ws, bstartF, recB, cid,
                                              rep, N, b0, (int)cap);
  }

  head_kernel<<<1, 256, 0, stream>>>(ws, rep, endG, d_out, N);
}

// Round 12
// 243.277 us; speedup vs baseline: 1.0254x; 1.0254x over previous
//
#include <hip/hip_runtime.h>
#include <hip/hip_bf16.h>

#define HID 64
#define NGRAPH 16
#define BN 32            // nodes per bucket
#define GB 8             // buckets per coarse group (256 nodes, key = col>>8)
#define MAXNB 2048
#define NCB 256          // count/scatter blocks (256 = full CU coverage)
#define NCT 1024         // count/scatter threads (r14-verified)
#define SORT_T 1024
#define SORT_CHUNK 12800 // max records per group staged in LDS (avg ~8200)

typedef __attribute__((ext_vector_type(8))) short short8;
typedef __attribute__((ext_vector_type(4))) float f32x4;

// Fixed workspace layout (float offsets; all array bases 16B-aligned for float4)
enum : int {
  OFF_V      = 1040,
  OFF_M      = 1104,                  // unused since r15 (fold kept in LDS)
  OFF_EW1    = 5200,
  OFF_EB1    = 5520,
  OFF_NW1    = 5584,
  OFF_NB1    = 9744,
  OFF_NW2    = 9808,
  OFF_NB2    = 13904,
  OFF_OW1    = 13968,
  OFF_OB1    = 18064,
  OFF_OW2    = 18128,
  OFF_OB2    = 22224,
  OFF_OW3    = 22288,
  OFF_OB3    = 26384,
  OFF_OW4    = 26448,
  OFF_OB4    = 26576,
  OFF_EW2    = 26580,
  OFF_EB2    = 30676,
  OFF_FLAGS  = 30740,                 // 2 ints: [0]=ft (1=bf16), [1]=it (1=int64)
  OFF_W1T    = 30744,                 // 512 shorts (64 feats x 8 k)
  OFF_MT     = 31000,                 // 4096 shorts (M^T bf16)
  OFF_PREP   = 33048                  // rep: 8 pooled replicas * 16*64
};

struct WPtrs { const void* p[16]; };

__device__ __forceinline__ float cv(float v) { return v; }
__device__ __forceinline__ float cv(__hip_bfloat16 v) { return __bfloat162float(v); }
__device__ __forceinline__ float b2f(unsigned short u) {
  union { unsigned u32; float f; } c;
  c.u32 = ((unsigned)u) << 16;
  return c.f;
}
__device__ __forceinline__ unsigned short f2bu(float v) {   // cold path only
  union { __hip_bfloat16 b; unsigned short u; } c;
  c.b = __float2bfloat16(v);
  return c.u;
}
// fast RNE f32->bf16 (finite inputs): 3 VALU inst
__device__ __forceinline__ unsigned short fr(float v) {
  unsigned u = __float_as_uint(v);
  u += 0x7FFFu + ((u >> 16) & 1u);
  return (unsigned short)(u >> 16);
}
// relu + RNE-pack two floats into one dword via HW cvt_pk (lo = a, hi = b).
// r21-verified: replaces rndpack (9 VALU / 2 floats) with fmax x2 + 1 cvt_pk.
__device__ __forceinline__ unsigned cvtpk(float a, float b) {
  unsigned r;
  asm("v_cvt_pk_bf16_f32 %0, %1, %2"
      : "=v"(r) : "v"(fmaxf(a, 0.0f)), "v"(fmaxf(b, 0.0f)));
  return r;
}

// ---------------------------------------------------------------------------
// prep (r15-verified: 1024 threads, vectorized).
// ---------------------------------------------------------------------------
__global__ __launch_bounds__(1024) void prep_kernel(
    const void* xv, const void* eiv, WPtrs wp, float* ws)
{
  __shared__ int red[2];
  __shared__ int s_ft;
  __shared__ float ew2s[4096];
  __shared__ float nw1s[4096];
  const int t = threadIdx.x;
  const int lane = t & 63;

  if (t == 0) { red[0] = 0; red[1] = 0; }
  __syncthreads();
  {
    int big = 0;
    if (t < 512) {
      const unsigned el = (((const unsigned*)xv)[t] >> 7) & 0xFFu;
      big = (el >= 140u) ? 1 : 0;
    }
    #pragma unroll
    for (int o = 32; o > 0; o >>= 1) big += __shfl_xor(big, o);
    if (lane == 0 && big) atomicAdd(&red[0], big);
  }
  {
    int orv = ((const int*)eiv)[1 + 2 * t];
    #pragma unroll
    for (int o = 32; o > 0; o >>= 1) orv |= __shfl_xor(orv, o);
    if (lane == 0 && orv) atomicOr(&red[1], orv);
  }
  __syncthreads();
  if (t == 0) {
    const int ft = (red[0] < 8) ? 1 : 0;
    const int it = (red[1] == 0) ? 1 : 0;
    ((int*)(ws + OFF_FLAGS))[0] = ft;
    ((int*)(ws + OFF_FLAGS))[1] = it;
    s_ft = ft;
  }
  __syncthreads();
  const int ft = s_ft;

  const int sz[16]  = {320,64,4096,64,4160,64,4096,64,4096,64,4096,64,4096,64,128,2};
  const int dst[16] = {OFF_EW1,OFF_EB1,OFF_EW2,OFF_EB2,OFF_NW1,OFF_NB1,OFF_NW2,OFF_NB2,
                       OFF_OW1,OFF_OB1,OFF_OW2,OFF_OB2,OFF_OW3,OFF_OB3,OFF_OW4,OFF_OB4};
  for (int a = 0; a < 16; ++a) {
    const void* src = wp.p[a];
    float* d = ws + dst[a];
    const int n = sz[a];
    const int n4 = n >> 2;
    for (int i = t; i < n4; i += 1024) {
      float4 f;
      if (ft) {
        const ushort4 u4 = ((const ushort4*)src)[i];
        f.x = b2f(u4.x); f.y = b2f(u4.y); f.z = b2f(u4.z); f.w = b2f(u4.w);
      } else {
        f = ((const float4*)src)[i];
      }
      ((float4*)d)[i] = f;
      const int g = i << 2;
      if (a == 2) {
        ew2s[g] = f.x; ew2s[g + 1] = f.y; ew2s[g + 2] = f.z; ew2s[g + 3] = f.w;
      } else if (a == 4 && g >= 64) {
        nw1s[g - 64] = f.x; nw1s[g - 63] = f.y; nw1s[g - 62] = f.z; nw1s[g - 61] = f.w;
      }
    }
    for (int i = (n4 << 2) + t; i < n; i += 1024)
      d[i] = ft ? b2f(((const unsigned short*)src)[i]) : ((const float*)src)[i];
  }
  __syncthreads();

  // fold: M = EW2 @ NW1[1:], v = EB2 @ NW1[1:]  (4 outputs/thread)
  float mv[4];
  #pragma unroll
  for (int p = 0; p < 4; ++p) {
    const int idx = t + p * 1024;
    const int i = idx >> 6, j = idx & 63;
    float s = 0.0f;
    #pragma unroll 8
    for (int k = 0; k < 64; ++k)
      s = fmaf(ew2s[i * 64 + k], nw1s[k * 64 + j], s);
    mv[p] = s;
  }
  if (t < 64) {
    float s = 0.0f;
    #pragma unroll 8
    for (int k = 0; k < 64; ++k)
      s = fmaf(ws[OFF_EB2 + k], nw1s[k * 64 + t], s);
    ws[OFF_V + t] = s;
  }
  __syncthreads();
  #pragma unroll
  for (int p = 0; p < 4; ++p) ew2s[t + p * 1024] = mv[p];   // M now lives in ew2s
  __syncthreads();

  if (t < 64) {
    unsigned short* w1t = (unsigned short*)(ws + OFF_W1T);
    #pragma unroll
    for (int k = 0; k < 8; ++k) {
      float v = 0.0f;
      if (k < 5) v = ws[OFF_EW1 + k * 64 + t];
      else if (k == 5) v = ws[OFF_EB1 + t];
      w1t[t * 8 + k] = f2bu(v);
    }
  }
  unsigned short* mt = (unsigned short*)(ws + OFF_MT);
  #pragma unroll
  for (int p = 0; p < 4; ++p) {
    const int idx = t + p * 1024;
    const int n = idx >> 6, k = idx & 63;
    mt[idx] = f2bu(ew2s[k * 64 + n]);
  }
}

// ---------------------------------------------------------------------------
// count (+ merged bounds): per-block LDS histogram over COARSE GROUPS.
// r22: 2-pair batching (4 edges/iter) -- both pairs' loads issue upfront,
// doubling MLP in the latency-bound edge walk.
// ---------------------------------------------------------------------------
template<typename IT>
__device__ __forceinline__ void count_impl(
    const IT* __restrict__ ei, const IT* __restrict__ bt,
    int* __restrict__ gcnt, int* __restrict__ endG, int* lh,
    const int E, const int N, const int NBG)
{
  const int t = threadIdx.x;
  const int b = blockIdx.x;
  for (int i = t; i < NBG; i += NCT) lh[i] = 0;
  {
    const int i = b * NCT + t;            // merged bounds pass
    if (i < N) {
      const int g1 = (int)bt[i];
      if (i == 0) for (int g = 0; g < g1; ++g) endG[g] = 0;
      if (i == N - 1) {
        for (int g = g1; g < NGRAPH; ++g) endG[g] = N;
      } else {
        const int g2 = (int)bt[i + 1];
        for (int g = g1; g < g2; ++g) endG[g] = i + 1;
      }
    }
  }
  __syncthreads();
  const int per = (E + NCB - 1) / NCB;
  const int a = b * per;
  const int bnd = (a + per < E) ? (a + per) : E;
  const IT* col = ei + E;
  if ((E & 1) == 0) {                       // vector path (16B-aligned pairs)
    const int pa = (a + 1) >> 1;
    const int pb = bnd >> 1;
    if ((a & 1) && a < bnd && t == 0)
      atomicAdd(&lh[(int)col[a] >> 8], 1);
    if ((bnd & 1) && bnd - 1 >= a && t == NCT - 1)
      atomicAdd(&lh[(int)col[bnd - 1] >> 8], 1);
    for (int p = pa + t; p < pb; p += 2 * NCT) {
      const int p2 = p + NCT;
      const bool h2 = p2 < pb;
      int c0, c1, c2 = 0, c3 = 0;
      if constexpr (sizeof(IT) == 8) {
        const int4 v = ((const int4*)col)[p];
        c0 = v.x; c1 = v.z;
        if (h2) { const int4 w = ((const int4*)col)[p2]; c2 = w.x; c3 = w.z; }
      } else {
        const int2 v = ((const int2*)col)[p];
        c0 = v.x; c1 = v.y;
        if (h2) { const int2 w = ((const int2*)col)[p2]; c2 = w.x; c3 = w.y; }
      }
      atomicAdd(&lh[c0 >> 8], 1);
      atomicAdd(&lh[c1 >> 8], 1);
      if (h2) {
        atomicAdd(&lh[c2 >> 8], 1);
        atomicAdd(&lh[c3 >> 8], 1);
      }
    }
  } else {
    for (int e = a + t; e < bnd; e += NCT)
      atomicAdd(&lh[(int)col[e] >> 8], 1);
  }
  __syncthreads();
  for (int i = t; i < NBG; i += NCT) gcnt[(size_t)i * NCB + b] = lh[i];
}

__global__ __launch_bounds__(NCT) void count_kernel(
    const void* eiv, const void* batv, const float* ws,
    int* gcnt, int* endG, const int E, const int N, const int NBG)
{
  __shared__ int lh[MAXNB];
  const int it = ((const int*)(ws + OFF_FLAGS))[1];
  if (it) count_impl<long long>((const long long*)eiv, (const long long*)batv, gcnt, endG, lh, E, N, NBG);
  else    count_impl<int>((const int*)eiv, (const int*)batv, gcnt, endG, lh, E, N, NBG);
}

// ---------------------------------------------------------------------------
// scan (r22: reverted to the r20-verified 3-kernel parallel chain -- the r21
// single-block merge cost ~5-8 us: one latency-bound block vs 49 parallel).
// ---------------------------------------------------------------------------
__global__ __launch_bounds__(256) void scan_tot_kernel(
    const int* __restrict__ gcnt, int* __restrict__ gstart, const int NBG)
{
  const int lane = threadIdx.x & 63;
  const int bkt = blockIdx.x * 4 + (threadIdx.x >> 6);
  if (bkt >= NBG) return;
  const int4 v = *(const int4*)(gcnt + (size_t)bkt * NCB + lane * 4);
  int s = v.x + v.y + v.z + v.w;
  #pragma unroll
  for (int off = 32; off > 0; off >>= 1) s += __shfl_xor(s, off);
  if (lane == 0) gstart[bkt] = s;
}

__global__ __launch_bounds__(256) void scan_pref_kernel(
    int* __restrict__ gstart, const int NBG)
{
  __shared__ int ps[256];
  const int t = threadIdx.x;
  const int seg = (NBG + 255) / 256;
  int s = 0;
  for (int i = 0; i < seg; ++i) {
    const int idx = t * seg + i;
    if (idx < NBG) s += gstart[idx];
  }
  ps[t] = s;
  __syncthreads();
  for (int off = 1; off < 256; off <<= 1) {
    const int v = (t >= off) ? ps[t - off] : 0;
    __syncthreads();
    ps[t] += v;
    __syncthreads();
  }
  int carry = ps[t] - s;
  for (int i = 0; i < seg; ++i) {
    const int idx = t * seg + i;
    if (idx < NBG) {
      const int c = gstart[idx];
      gstart[idx] = carry;
      carry += c;
    }
  }
  if (t == 255) gstart[NBG] = ps[255];
}

__global__ __launch_bounds__(256) void scan_row_kernel(
    int* __restrict__ gcnt, const int* __restrict__ gstart, const int NBG)
{
  const int lane = threadIdx.x & 63;
  const int bkt = blockIdx.x * 4 + (threadIdx.x >> 6);
  if (bkt >= NBG) return;
  int* row = gcnt + (size_t)bkt * NCB;
  const int4 v = *(const int4*)(row + lane * 4);
  const int ls = v.x + v.y + v.z + v.w;
  int s = ls;
  #pragma unroll
  for (int off = 1; off < 64; off <<= 1) {
    const int u = __shfl_up(s, off);
    if (lane >= off) s += u;
  }
  int e = s - ls + gstart[bkt];
  int4 o;
  o.x = e; e += v.x;
  o.y = e; e += v.y;
  o.z = e; e += v.z;
  o.w = e;
  *(int4*)(row + lane * 4) = o;
}

// ---------------------------------------------------------------------------
// scatter pass 1: write bf16 payload recB[pos]={xr,a0,a1,a2} + cid[pos]=col&255
// sorted by COARSE GROUP only. r22: 2-pair batching (4 edges/iter) with all
// index/attr loads and x-gathers issued before the atomic/store sequence.
// ---------------------------------------------------------------------------
template<typename FT, typename IT>
__device__ __forceinline__ void scat_one(
    const FT* __restrict__ x, const IT* __restrict__ ei, const FT* __restrict__ ea,
    int* lb, ushort4* __restrict__ recB, unsigned char* __restrict__ cid,
    const int E, const int e, const int gb0, const int gb1, const int cap)
{
  const int c = (int)ei[(size_t)E + e];
  const int grp = c >> 8;
  if (grp >= gb0 && grp < gb1) {
    const int pos = atomicAdd(&lb[grp - gb0], 1);
    if (pos < cap) {
      const int r = (int)ei[e];
      ushort4 rv;
      rv.x = fr(cv(x[r]));
      rv.y = fr(cv(ea[(size_t)3 * e + 0]));
      rv.z = fr(cv(ea[(size_t)3 * e + 1]));
      rv.w = fr(cv(ea[(size_t)3 * e + 2]));
      recB[pos] = rv;
      cid[pos] = (unsigned char)(c & 255);
    }
  }
}

template<typename FT, typename IT>
__device__ __forceinline__ void scatter_impl(
    const FT* __restrict__ x, const IT* __restrict__ ei, const FT* __restrict__ ea,
    const int* __restrict__ gcnt, const int* __restrict__ gstart,
    ushort4* __restrict__ recB, unsigned char* __restrict__ cid, int* lb,
    const int E, const int gb0, const int gb1, const int cap)
{
  const int t = threadIdx.x;
  const int b = blockIdx.x;
  __shared__ int sbase;
  if (t == 0) sbase = gstart[gb0];
  __syncthreads();
  const int base = sbase;
  const int gcount = gb1 - gb0;
  for (int i = t; i < gcount; i += NCT) lb[i] = gcnt[(size_t)(gb0 + i) * NCB + b] - base;
  __syncthreads();

  const int per = (E + NCB - 1) / NCB;
  const int a = b * per;
  const int bnd = (a + per < E) ? (a + per) : E;
  for (int e = a + t; e < bnd; e += NCT)
    scat_one<FT, IT>(x, ei, ea, lb, recB, cid, E, e, gb0, gb1, cap);
}

// emit one edge's record from pre-loaded values
__device__ __forceinline__ void emit_rec(
    int* lb, ushort4* __restrict__ recB, unsigned char* __restrict__ cid,
    const int c, const unsigned short xr,
    const unsigned short a0, const unsigned short a1, const unsigned short a2,
    const int gb0, const int gb1, const int cap)
{
  const int g = c >> 8;
  if (g >= gb0 && g < gb1) {
    const int pos = atomicAdd(&lb[g - gb0], 1);
    if (pos < cap) {
      ushort4 rv;
      rv.x = xr; rv.y = a0; rv.z = a1; rv.w = a2;
      recB[pos] = rv;
      cid[pos] = (unsigned char)(c & 255);
    }
  }
}

// bf16 + even-E fast path: 2-pair batching, vector loads, raw bit payload copy.
template<typename IT>
__device__ __forceinline__ void scatter_fast(
    const unsigned short* __restrict__ x, const IT* __restrict__ ei,
    const void* __restrict__ eav,
    const int* __restrict__ gcnt, const int* __restrict__ gstart,
    ushort4* __restrict__ recB, unsigned char* __restrict__ cid, int* lb,
    const int E, const int gb0, const int gb1, const int cap)
{
  const int t = threadIdx.x;
  const int b = blockIdx.x;
  __shared__ int sbase2;
  if (t == 0) sbase2 = gstart[gb0];
  __syncthreads();
  const int base = sbase2;
  const int gcount = gb1 - gb0;
  for (int i = t; i < gcount; i += NCT) lb[i] = gcnt[(size_t)(gb0 + i) * NCB + b] - base;
  __syncthreads();

  const int per = (E + NCB - 1) / NCB;
  const int a = b * per;
  const int bnd = (a + per < E) ? (a + per) : E;
  const int pa = (a + 1) >> 1;
  const int pb = bnd >> 1;

  // head/tail odd edges via scalar helper (bf16 view)
  const __hip_bfloat16* xb = (const __hip_bfloat16*)x;
  const __hip_bfloat16* eab = (const __hip_bfloat16*)eav;
  if ((a & 1) && a < bnd && t == 0)
    scat_one<__hip_bfloat16, IT>(xb, ei, eab, lb, recB, cid, E, a, gb0, gb1, cap);
  if ((bnd & 1) && bnd - 1 >= a && t == NCT - 1)
    scat_one<__hip_bfloat16, IT>(xb, ei, eab, lb, recB, cid, E, bnd - 1, gb0, gb1, cap);

  const IT* col = ei + E;
  for (int p = pa + t; p < pb; p += 2 * NCT) {
    const int p2 = p + NCT;
    const bool h2 = p2 < pb;

    // batch A loads
    int c0, c1, r0, r1;
    if constexpr (sizeof(IT) == 8) {
      const int4 vc = ((const int4*)col)[p];
      c0 = vc.x; c1 = vc.z;
      const int4 vr = ((const int4*)ei)[p];
      r0 = vr.x; r1 = vr.z;
    } else {
      const int2 vc = ((const int2*)col)[p];
      c0 = vc.x; c1 = vc.y;
      const int2 vr = ((const int2*)ei)[p];
      r0 = vr.x; r1 = vr.y;
    }
    const uint3 d = ((const uint3*)eav)[p];

    // batch B loads (independent; issue before any dependent use)
    int c0b = 0, c1b = 0, r0b = 0, r1b = 0;
    uint3 db = make_uint3(0, 0, 0);
    if (h2) {
      if constexpr (sizeof(IT) == 8) {
        const int4 vc = ((const int4*)col)[p2];
        c0b = vc.x; c1b = vc.z;
        const int4 vr = ((const int4*)ei)[p2];
        r0b = vr.x; r1b = vr.z;
      } else {
        const int2 vc = ((const int2*)col)[p2];
        c0b = vc.x; c1b = vc.y;
        const int2 vr = ((const int2*)ei)[p2];
        r0b = vr.x; r1b = vr.y;
      }
      db = ((const uint3*)eav)[p2];
    }

    // x gathers for all 4 edges (issue together)
    const unsigned short x0 = x[r0];
    const unsigned short x1 = x[r1];
    const unsigned short x0b = h2 ? x[r0b] : (unsigned short)0;
    const unsigned short x1b = h2 ? x[r1b] : (unsigned short)0;

    emit_rec(lb, recB, cid, c0, x0,
             (unsigned short)(d.x & 0xFFFFu), (unsigned short)(d.x >> 16),
             (unsigned short)(d.y & 0xFFFFu), gb0, gb1, cap);
    emit_rec(lb, recB, cid, c1, x1,
             (unsigned short)(d.y >> 16), (unsigned short)(d.z & 0xFFFFu),
             (unsigned short)(d.z >> 16), gb0, gb1, cap);
    if (h2) {
      emit_rec(lb, recB, cid, c0b, x0b,
               (unsigned short)(db.x & 0xFFFFu), (unsigned short)(db.x >> 16),
               (unsigned short)(db.y & 0xFFFFu), gb0, gb1, cap);
      emit_rec(lb, recB, cid, c1b, x1b,
               (unsigned short)(db.y >> 16), (unsigned short)(db.z & 0xFFFFu),
               (unsigned short)(db.z >> 16), gb0, gb1, cap);
    }
  }
}

__global__ __launch_bounds__(NCT) void scatter_kernel(
    const void* xv, const void* eiv, const void* eav, const float* ws,
    const int* gcnt, const int* gstart, ushort4* recB, unsigned char* cid,
    const int E, const int gb0, const int gb1, const int cap)
{
  __shared__ int lb[MAXNB];
  const int* fl = (const int*)(ws + OFF_FLAGS);
  const int ft = fl[0], it = fl[1];
  if (ft && ((E & 1) == 0)) {
    if (it) scatter_fast<long long>((const unsigned short*)xv, (const long long*)eiv, eav, gcnt, gstart, recB, cid, lb, E, gb0, gb1, cap);
    else    scatter_fast<int>((const unsigned short*)xv, (const int*)eiv, eav, gcnt, gstart, recB, cid, lb, E, gb0, gb1, cap);
  } else if (ft) {
    if (it) scatter_impl<__hip_bfloat16, long long>((const __hip_bfloat16*)xv, (const long long*)eiv, (const __hip_bfloat16*)eav, gcnt, gstart, recB, cid, lb, E, gb0, gb1, cap);
    else    scatter_impl<__hip_bfloat16, int>((const __hip_bfloat16*)xv, (const int*)eiv, (const __hip_bfloat16*)eav, gcnt, gstart, recB, cid, lb, E, gb0, gb1, cap);
  } else {
    if (it) scatter_impl<float, long long>((const float*)xv, (const long long*)eiv, (const float*)eav, gcnt, gstart, recB, cid, lb, E, gb0, gb1, cap);
    else    scatter_impl<float, int>((const float*)xv, (const int*)eiv, (const float*)eav, gcnt, gstart, recB, cid, lb, E, gb0, gb1, cap);
  }
}

// ---------------------------------------------------------------------------
// sort pass 2: one block per coarse group; LDS-staged in-place fine sort.
// ---------------------------------------------------------------------------
__global__ __launch_bounds__(SORT_T) void sort_kernel(
    ushort4* __restrict__ recB, unsigned char* __restrict__ cid,
    const int* __restrict__ gstart, int* __restrict__ bstartF,
    const int NB, const int gr0, const int cap)
{
  __shared__ unsigned sru[SORT_CHUNK * 2];     // 102.4 KB record payload
  __shared__ unsigned char sc[SORT_CHUNK];     // 12.8 KB keys
  __shared__ int h2[16][GB];                   // per-wave histograms
  __shared__ int fs[GB];
  __shared__ int cur[GB];

  const int t = threadIdx.x;
  const int lane = t & 63;
  const int wav = t >> 6;
  const int g = gr0 + (int)blockIdx.x;

  const int base0 = gstart[gr0];
  int rb = gstart[g] - base0;
  int re = gstart[g + 1] - base0;
  if (rb > cap) rb = cap;
  if (re > cap) re = cap;
  int cnt = re - rb;
  if (cnt > SORT_CHUNK) cnt = SORT_CHUNK;

  if (t < 16 * GB) ((int*)h2)[t] = 0;
  __syncthreads();

  // stage to LDS + per-wave histogram (ballot-aggregated, no atomics)
  for (int i = t; i < cnt; i += SORT_T) {
    const ushort4 r = recB[rb + i];
    sru[2 * i]     = (unsigned)r.x | ((unsigned)r.y << 16);
    sru[2 * i + 1] = (unsigned)r.z | ((unsigned)r.w << 16);
    const unsigned char c = cid[rb + i];
    sc[i] = c;
    const int kk = c >> 5;
    unsigned long long mym = 0;
    #pragma unroll
    for (int k = 0; k < GB; ++k) {
      const unsigned long long bk = __ballot(kk == k);
      if (kk == k) mym = bk;
    }
    if ((mym & (((unsigned long long)1 << lane) - 1ull)) == 0)   // leader per key
      h2[wav][kk] += (int)__builtin_popcountll(mym);
  }
  __syncthreads();

  if (t == 0) {
    int acc = 0;
    for (int k = 0; k < GB; ++k) {
      int s = 0;
      #pragma unroll
      for (int w = 0; w < 16; ++w) s += h2[w][k];
      fs[k] = acc;
      cur[k] = acc;
      acc += s;
    }
  }
  __syncthreads();

  // fine bucket starts (absolute)
  if (t <= GB) {
    const int bk = g * GB + t;
    if (bk <= NB) bstartF[bk] = base0 + rb + ((t == GB) ? cnt : fs[t]);
  }

  // in-place scatter to final bucket-sorted positions
  for (int i = t; i < cnt; i += SORT_T) {
    const unsigned char c = sc[i];
    const int kk = c >> 5;
    unsigned long long mym = 0;
    #pragma unroll
    for (int k = 0; k < GB; ++k) {
      const unsigned long long bk = __ballot(kk == k);
      if (kk == k) mym = bk;
    }
    const int lead = (int)__builtin_ctzll(mym);
    const int off = (int)__builtin_popcountll(mym & (((unsigned long long)1 << lane) - 1ull));
    int bas = 0;
    if (lane == lead) bas = atomicAdd(&cur[kk], (int)__builtin_popcountll(mym));
    bas = __shfl(bas, lead);
    const int pos = rb + bas + off;
    const unsigned a = sru[2 * i], b = sru[2 * i + 1];
    ushort4 rv;
    rv.x = (unsigned short)(a & 0xFFFFu); rv.y = (unsigned short)(a >> 16);
    rv.z = (unsigned short)(b & 0xFFFFu); rv.w = (unsigned short)(b >> 16);
    recB[pos] = rv;
    cid[pos] = (unsigned char)(c & 31);
  }
}

// ---------------------------------------------------------------------------
// fused (cooperative MFMA, r19/r21-verified): pair-phase schedule, incremental
// one-hot, reg-held A1, scalar prefetch, cvt_pk bf16 conversion.
// ---------------------------------------------------------------------------

#define FUSED_H(J, RV, CC)                                                       \
    if ((J) < jmax) {                                                            \
      short* HT = sHT + ((J) & 1) * 4608;                                        \
      short8 a1;                                                                 \
      if (quad == 0) {                                                           \
        const bool vv = (CC) < 32;                                               \
        a1[0] = (short)(RV).x;                                                   \
        a1[1] = vv ? (short)xlsb[(CC)] : (short)0;                               \
        a1[2] = (short)(RV).y; a1[3] = (short)(RV).z; a1[4] = (short)(RV).w;     \
        a1[5] = vv ? (short)0x3F80 : (short)0;                                   \
        a1[6] = 0; a1[7] = 0;                                                    \
      } else {                                                                   \
        a1[0]=0; a1[1]=0; a1[2]=0; a1[3]=0; a1[4]=0; a1[5]=0; a1[6]=0; a1[7]=0;  \
      }                                                                          \
      f32x4 Hc0 = __builtin_amdgcn_mfma_f32_16x16x32_bf16(a1, B1[0], (f32x4)0.0f, 0, 0, 0); \
      f32x4 Hc1 = __builtin_amdgcn_mfma_f32_16x16x32_bf16(a1, B1[1], (f32x4)0.0f, 0, 0, 0); \
      f32x4 Hc2 = __builtin_amdgcn_mfma_f32_16x16x32_bf16(a1, B1[2], (f32x4)0.0f, 0, 0, 0); \
      f32x4 Hc3 = __builtin_amdgcn_mfma_f32_16x16x32_bf16(a1, B1[3], (f32x4)0.0f, 0, 0, 0); \
      uint2 pk0, pk1, pk2, pk3;                                                  \
      pk0.x = cvtpk(Hc0[0], Hc0[1]); pk0.y = cvtpk(Hc0[2], Hc0[3]);              \
      pk1.x = cvtpk(Hc1[0], Hc1[1]); pk1.y = cvtpk(Hc1[2], Hc1[3]);              \
      pk2.x = cvtpk(Hc2[0], Hc2[1]); pk2.y = cvtpk(Hc2[2], Hc2[3]);              \
      pk3.x = cvtpk(Hc3[0], Hc3[1]); pk3.y = cvtpk(Hc3[2], Hc3[3]);              \
      *(uint2*)(HT + ( 0 + l15) * 72 + 16 * wav + quad * 4) = pk0;               \
      *(uint2*)(HT + (16 + l15) * 72 + 16 * wav + quad * 4) = pk1;               \
      *(uint2*)(HT + (32 + l15) * 72 + 16 * wav + quad * 4) = pk2;               \
      *(uint2*)(HT + (48 + l15) * 72 + 16 * wav + quad * 4) = pk3;               \
    }

#define FUSED_PV(J)                                                             \
    if ((J) < jmax) {                                                           \
      const short* HT = sHT + ((J) & 1) * 4608;                                 \
      const short* aj = a2L + (J) * 2304;                                       \
      _Pragma("unroll")                                                         \
      for (int q = 0; q < 2; ++q) {                                             \
        const short8 a20 = *(const short8*)(aj + l15 * 72 + 32 * q + 8 * quad); \
        const short8 a21 = *(const short8*)(aj + (16 + l15) * 72 + 32 * q + 8 * quad); \
        const short8 b2  = *(const short8*)(HT + (16 * wav + l15) * 72 + 32 * q + quad * 8); \
        C2[0] = __builtin_amdgcn_mfma_f32_16x16x32_bf16(a20, b2, C2[0], 0, 0, 0);\
        C2[1] = __builtin_amdgcn_mfma_f32_16x16x32_bf16(a21, b2, C2[1], 0, 0, 0);\
        C3[0] = __builtin_amdgcn_mfma_f32_16x16x32_bf16(a20, ONES8, C3[0], 0, 0, 0); \
        C3[1] = __builtin_amdgcn_mfma_f32_16x16x32_bf16(a21, ONES8, C3[1], 0, 0, 0); \
      }                                                                         \
    }

template<typename FT, typename IT>
__device__ __forceinline__ void fused_impl(
    const FT* __restrict__ x, const IT* __restrict__ batch,
    const float* __restrict__ ws, const int* __restrict__ bstart,
    const ushort4* __restrict__ recB, const unsigned char* __restrict__ cid,
    float* __restrict__ rep,
    short* sHT, short* a2L,
    float* xls, unsigned short* xlsb, int* sbi,
    const int N, const int gb0, const int cap)
{
  const int t = threadIdx.x;
  const int lane = t & 63;
  const int quad = lane >> 4;
  const int l15 = lane & 15;
  const int wav = t >> 6;
  const int bucket = gb0 + blockIdx.x;

  // initial full zero of a2L (once; afterwards incrementally maintained)
  {
    unsigned long long* az = (unsigned long long*)a2L;
    #pragma unroll
    for (int z = 0; z < 9; ++z) az[t + z * 256] = 0ull;
  }
  if (t < BN) {
    const int n = bucket * BN + t;
    const float xvv = (n < N) ? cv(x[n]) : 0.0f;
    xls[t] = xvv;
    xlsb[t] = fr(xvv);
  }
  if (t == 0) {
    const int nf = bucket * BN, nl = bucket * BN + BN - 1;
    sbi[0] = (int)batch[(nf < N) ? nf : (N - 1)];
    sbi[1] = (int)batch[(nl < N) ? nl : (N - 1)];
    sbi[2] = bstart[gb0];
  }
  __syncthreads();

  const unsigned short* w1t = (const unsigned short*)(ws + OFF_W1T);
  short8 B1[4];
  #pragma unroll
  for (int tn = 0; tn < 4; ++tn) {
    short8 z; for (int j = 0; j < 8; ++j) z[j] = 0;
    if (quad == 0) z = *(const short8*)(w1t + (16 * tn + l15) * 8);
    B1[tn] = z;
  }
  short8 ONES8;
  #pragma unroll
  for (int j = 0; j < 8; ++j) ONES8[j] = (short)0x3F80;

  const int base = sbi[2];
  int s0 = bstart[bucket] - base;
  int e0 = bstart[bucket + 1] - base;
  if (s0 > cap) s0 = cap;
  if (e0 > cap) e0 = cap;

  f32x4 C2[2]; C2[0] = (f32x4)0.0f; C2[1] = (f32x4)0.0f;
  f32x4 C3[2]; C3[0] = (f32x4)0.0f; C3[1] = (f32x4)0.0f;

  const int nedge = e0 - s0;
  const int nst = (nedge + 255) >> 8;

  // quad-0 lane (wav,l15) owns edges 64*j + 16*wav + l15 of each stage.
  const ushort4 uz = make_ushort4(0, 0, 0, 0);
  ushort4 rv0 = uz, rv1 = uz, rv2 = uz, rv3 = uz;
  int c0 = 255, c1 = 255, c2 = 255, c3 = 255;
  int cp0 = 255, cp1 = 255, cp2 = 255, cp3 = 255;   // previously-set one-hot col
  if (nst > 0 && quad == 0) {
    int idx;
    idx = s0 +   0 + 16 * wav + l15; if (idx < e0) { rv0 = recB[idx]; c0 = (int)cid[idx]; }
    idx = s0 +  64 + 16 * wav + l15; if (idx < e0) { rv1 = recB[idx]; c1 = (int)cid[idx]; }
    idx = s0 + 128 + 16 * wav + l15; if (idx < e0) { rv2 = recB[idx]; c2 = (int)cid[idx]; }
    idx = s0 + 192 + 16 * wav + l15; if (idx < e0) { rv3 = recB[idx]; c3 = (int)cid[idx]; }
  }

  for (int st = 0; st < nst; ++st) {
    const int m = nedge - st * 256;
    const int jmax = (m >= 256) ? 4 : ((m + 63) >> 6);

    // incremental one-hot update (same-thread slot ownership)
    if (quad == 0) {
      const int row = 16 * wav + l15;
      if (cp0 != c0) { if (cp0 < 32) a2L[0 * 2304 + cp0 * 72 + row] = 0;
                       if (c0  < 32) a2L[0 * 2304 + c0  * 72 + row] = (short)0x3F80; }
      if (cp1 != c1) { if (cp1 < 32) a2L[1 * 2304 + cp1 * 72 + row] = 0;
                       if (c1  < 32) a2L[1 * 2304 + c1  * 72 + row] = (short)0x3F80; }
      if (cp2 != c2) { if (cp2 < 32) a2L[2 * 2304 + cp2 * 72 + row] = 0;
                       if (c2  < 32) a2L[2 * 2304 + c2  * 72 + row] = (short)0x3F80; }
      if (cp3 != c3) { if (cp3 < 32) a2L[3 * 2304 + cp3 * 72 + row] = 0;
                       if (c3  < 32) a2L[3 * 2304 + c3  * 72 + row] = (short)0x3F80; }
    }
    cp0 = c0; cp1 = c1; cp2 = c2; cp3 = c3;

    // prefetch next stage into scalar regs; HBM latency hides under MFMA
    ushort4 nv0 = uz, nv1 = uz, nv2 = uz, nv3 = uz;
    int n0 = 255, n1 = 255, n2 = 255, n3 = 255;
    if (st + 1 < nst && quad == 0) {
      const int nb = s0 + (st + 1) * 256 + 16 * wav + l15;
      int idx;
      idx = nb;       if (idx < e0) { nv0 = recB[idx]; n0 = (int)cid[idx]; }
      idx = nb +  64; if (idx < e0) { nv1 = recB[idx]; n1 = (int)cid[idx]; }
      idx = nb + 128; if (idx < e0) { nv2 = recB[idx]; n2 = (int)cid[idx]; }
      idx = nb + 192; if (idx < e0) { nv3 = recB[idx]; n3 = (int)cid[idx]; }
    }

    FUSED_H(0, rv0, c0)
    FUSED_H(1, rv1, c1)
    __syncthreads();
    FUSED_PV(0)
    FUSED_PV(1)
    __syncthreads();
    if (jmax > 2) {
      FUSED_H(2, rv2, c2)
      FUSED_H(3, rv3, c3)
      __syncthreads();
      FUSED_PV(2)
      FUSED_PV(3)
      __syncthreads();
    }
    rv0 = nv0; c0 = n0; rv1 = nv1; c1 = n1;
    rv2 = nv2; c2 = n2; rv3 = nv3; c3 = n3;
  }

  short* aggB = a2L;   // overlay rows 0..31 (4608B); a2L dead after main loop
  #pragma unroll
  for (int tm2 = 0; tm2 < 2; ++tm2) {
    #pragma unroll
    for (int r = 0; r < 4; ++r)
      aggB[(16 * tm2 + quad * 4 + r) * 72 + 16 * wav + l15] = (short)fr(C2[tm2][r]);
  }
  __syncthreads();

  const unsigned short* mt = (const unsigned short*)(ws + OFF_MT);
  f32x4 D[2]; D[0] = (f32x4)0.0f; D[1] = (f32x4)0.0f;
  #pragma unroll
  for (int q2 = 0; q2 < 2; ++q2) {
    const short8 bb = *(const short8*)(mt + (16 * wav + l15) * 64 + 32 * q2 + quad * 8);
    #pragma unroll
    for (int tm2 = 0; tm2 < 2; ++tm2) {
      const short8 aa = *(const short8*)(aggB + (16 * tm2 + l15) * 72 + 32 * q2 + quad * 8);
      D[tm2] = __builtin_amdgcn_mfma_f32_16x16x32_bf16(aa, bb, D[tm2], 0, 0, 0);
    }
  }

  const int n = 16 * wav + l15;
  const float c1n = ws[OFF_NW1 + n];
  const float vn  = ws[OFF_V + n];
  const float bn  = ws[OFF_NB1 + n];
  float* myrep = rep + (size_t)(bucket & 7) * (NGRAPH * 64);
  const bool multi = (sbi[0] != sbi[1]);

  if (!multi) {
    // fast path: whole bucket in one graph -> quad-reduce + 1 atomic per (g,n)
    float hs = 0.0f;
    #pragma unroll
    for (int tm2 = 0; tm2 < 2; ++tm2) {
      #pragma unroll
      for (int r = 0; r < 4; ++r) {
        const int mrow = 16 * tm2 + quad * 4 + r;
        const int ng = bucket * BN + mrow;
        if (ng < N)
          hs += fmaxf(D[tm2][r] + xls[mrow] * c1n + C3[tm2][r] * vn + bn, 0.0f);
      }
    }
    hs += __shfl_xor(hs, 16);
    hs += __shfl_xor(hs, 32);
    if (quad == 0) unsafeAtomicAdd(&myrep[sbi[0] * 64 + n], hs);
  } else {
    float* pooledL = (float*)((char*)a2L + 4608);   // behind aggB rows, 4096B
    for (int i = t; i < NGRAPH * 64; i += 256) pooledL[i] = 0.0f;
    __syncthreads();
    #pragma unroll
    for (int tm2 = 0; tm2 < 2; ++tm2) {
      #pragma unroll
      for (int r = 0; r < 4; ++r) {
        const int mrow = 16 * tm2 + quad * 4 + r;
        const int ng = bucket * BN + mrow;
        if (ng < N) {
          const float h = fmaxf(D[tm2][r] + xls[mrow] * c1n + C3[tm2][r] * vn + bn, 0.0f);
          const int g = (int)batch[ng];
          atomicAdd(&pooledL[g * 64 + n], h);
        }
      }
    }
    __syncthreads();
    for (int g = sbi[0] + wav; g <= sbi[1]; g += 4)
      unsafeAtomicAdd(&myrep[g * 64 + lane], pooledL[g * 64 + lane]);
  }
}

__global__ __launch_bounds__(256, 4) void fused_kernel(
    const void* xv, const void* batv, const float* ws, const int* bstart,
    const ushort4* recB, const unsigned char* cid, float* rep,
    const int N, const int gb0, const int cap)
{
  // carved LDS (37.1 KB -> 4 blocks/CU): sHT dbuf 18432 | a2L/aggB/pooledL 18432 | misc
  __shared__ __align__(16) unsigned char smem[37072];
  short* sHT = (short*)smem;
  short* a2L = (short*)(smem + 18432);
  float* xls = (float*)(smem + 36864);
  unsigned short* xlsb = (unsigned short*)(smem + 36992);
  int* sbi = (int*)(smem + 37056);

  const int* fl = (const int*)(ws + OFF_FLAGS);
  const int ft = fl[0], it = fl[1];
  if (ft) {
    if (it) fused_impl<__hip_bfloat16, long long>((const __hip_bfloat16*)xv, (const long long*)batv, ws, bstart, recB, cid, rep, sHT, a2L, xls, xlsb, sbi, N, gb0, cap);
    else    fused_impl<__hip_bfloat16, int>((const __hip_bfloat16*)xv, (const int*)batv, ws, bstart, recB, cid, rep, sHT, a2L, xls, xlsb, sbi, N, gb0, cap);
  } else {
    if (it) fused_impl<float, long long>((const float*)xv, (const long long*)batv, ws, bstart, recB, cid, rep, sHT, a2L, xls, xlsb, sbi, N, gb0, cap);
    else    fused_impl<float, int>((const float*)xv, (const int*)batv, ws, bstart, recB, cid, rep, sHT, a2L, xls, xlsb, sbi, N, gb0, cap);
  }
}

// ---------------------------------------------------------------------------
// head: reduce 8 pooled replicas; cnt from precomputed endG; dense head.
// ---------------------------------------------------------------------------
__global__ __launch_bounds__(256) void head_kernel(
    const float* ws, const float* rep, const int* __restrict__ endG,
    void* outv, const int N)
{
  __shared__ float P[NGRAPH][HID];
  __shared__ float A[NGRAPH][HID];
  __shared__ float B[NGRAPH][HID];
  __shared__ int endL[NGRAPH];

  const int t = threadIdx.x;
  const int j = t & 63;
  const int gq = t >> 6;

  if (t < NGRAPH) endL[t] = endG[t];

  #pragma unroll
  for (int gi = 0; gi < 4; ++gi) {
    const int g = gq + gi * 4;
    float s = 0.0f;
    #pragma unroll
    for (int r = 0; r < 8; ++r)
      s += rep[(size_t)r * (NGRAPH * 64) + g * 64 + j];
    P[g][j] = s;
  }
  __syncthreads();

  {
    const float bj = ws[OFF_NB2 + j];
    #pragma unroll
    for (int gi = 0; gi < 4; ++gi) {
      const int g = gq + gi * 4;
      const float cg = (float)(endL[g] - (g ? endL[g - 1] : 0));
      float s = cg * bj;
      #pragma unroll 8
      for (int k = 0; k < HID; ++k)
        s = fmaf(P[g][k], ws[OFF_NW2 + k * HID + j], s);
      A[g][j] = s;
    }
  }
  __syncthreads();

  const int wOff[3] = {OFF_OW1, OFF_OW2, OFF_OW3};
  const int bOff[3] = {OFF_OB1, OFF_OB2, OFF_OB3};
  for (int L = 0; L < 3; ++L) {
    float (*In)[HID]  = (L & 1) ? B : A;
    float (*Out)[HID] = (L & 1) ? A : B;
    const float bj = ws[bOff[L] + j];
    #pragma unroll
    for (int gi = 0; gi < 4; ++gi) {
      const int g = gq + gi * 4;
      float s = bj;
      #pragma unroll 8
      for (int k = 0; k < HID; ++k)
        s = fmaf(In[g][k], ws[wOff[L] + k * HID + j], s);
      Out[g][j] = fmaxf(s, 0.0f);
    }
    __syncthreads();
  }

  if (t < 32) {
    const int g = t >> 1, d = t & 1;
    float s = ws[OFF_OB4 + d];
    #pragma unroll 8
    for (int k = 0; k < HID; ++k)
      s = fmaf(B[g][k], ws[OFF_OW4 + k * 2 + d], s);
    const int ft = ((const int*)(ws + OFF_FLAGS))[0];
    if (ft) ((__hip_bfloat16*)outv)[g * 2 + d] = __float2bfloat16(s);
    else    ((float*)outv)[g * 2 + d] = s;
  }
}

extern "C" void kernel_launch(void* const* d_in, const int* in_sizes, int n_in,
                              void* d_out, int out_size, void* d_ws, size_t ws_size,
                              hipStream_t stream)
{
  const void* xv   = d_in[0];
  const void* eiv  = d_in[1];
  const void* eav  = d_in[2];
  const void* batv = d_in[3];

  WPtrs wp;
  for (int a = 0; a < 16; ++a) wp.p[a] = d_in[4 + a];

  const int N = in_sizes[0];
  const int E = in_sizes[1] / 2;
  const int NB = (N + BN - 1) / BN;
  const int NBG = (NB + GB - 1) / GB;
  if (NB > MAXNB) return;

  float* ws    = (float*)d_ws;
  float* rep   = ws + OFF_PREP;                            // 8*1024 floats
  int* gstart  = (int*)(rep + 8 * NGRAPH * 64);            // NBG+1 ints
  int* bstartF = gstart + NBG + 1;                         // NB+2 ints
  int* endG    = bstartF + NB + 2;                         // 16 ints
  int* gcnt    = endG + NGRAPH;                            // NBG*NCB ints

  size_t recOffB = ((size_t)((char*)(gcnt + (size_t)NBG * NCB) - (char*)d_ws) + 15) & ~(size_t)15;

  int G = -1; long long cap = 0;
  for (int g = 1; g <= 64; ++g) {
    const long long c = (long long)E / g + E / 32 + 8192;
    if (recOffB + (size_t)c * 9 <= ws_size) { G = g; cap = c; break; }
  }
  if (G < 0) return;

  ushort4* recB = (ushort4*)((char*)d_ws + recOffB);
  unsigned char* cid = (unsigned char*)(recB + cap);
  const int gsz = (NBG + G - 1) / G;
  const int sblk = (NBG + 3) / 4;

  (void)hipMemsetAsync(rep, 0, (size_t)(8 * NGRAPH * 64) * 4, stream);

  prep_kernel<<<1, 1024, 0, stream>>>(xv, eiv, wp, ws);
  count_kernel<<<NCB, NCT, 0, stream>>>(eiv, batv, ws, gcnt, endG, E, N, NBG);
  scan_tot_kernel<<<sblk, 256, 0, stream>>>(gcnt, gstart, NBG);
  scan_pref_kernel<<<1, 256, 0, stream>>>(gstart, NBG);
  scan_row_kernel<<<sblk, 256, 0, stream>>>(gcnt, gstart, NBG);

  for (int g = 0; g < G; ++g) {
    const int gr0 = g * gsz;
    const int gr1 = (gr0 + gsz < NBG) ? (gr0 + gsz) : NBG;
    if (gr0 >= gr1) break;
    scatter_kernel<<<NCB, NCT, 0, stream>>>(xv, eiv, eav, ws, gcnt, gstart,
                                            recB, cid, E, gr0, gr1, (int)cap);
    sort_kernel<<<gr1 - gr0, SORT_T, 0, stream>>>(recB, cid, gstart, bstartF,
                                                  NB, gr0, (int)cap);
    const int b0 = gr0 * GB;
    const int b1 = (gr1 * GB < NB) ? (gr1 * GB) : NB;
    fused_kernel<<<b1 - b0, 256, 0, stream>>>(xv, batv, ws, bstartF, recB, cid,
                                              rep, N, b0, (int)cap);
  }

  head_kernel<<<1, 256, 0, stream>>>(ws, rep, endG, d_out, N);
}

// Round 13
// 243.017 us; speedup vs baseline: 1.0265x; 1.0011x over previous
//
#include <hip/hip_runtime.h>
#include <hip/hip_bf16.h>

#define HID 64
#define NGRAPH 16
#define BN 32            // nodes per bucket
#define GB 8             // buckets per coarse group (256 nodes, key = col>>8)
#define MAXNB 2048
#define NCB 512          // count/scatter blocks (r23: 256->512; 2 blocks/CU = 32 waves)
#define NCT 1024         // count/scatter threads (r14-verified)
#define SORT_T 1024
#define SORT_CHUNK 12800 // max records per group staged in LDS (avg ~8200)

typedef __attribute__((ext_vector_type(8))) short short8;
typedef __attribute__((ext_vector_type(4))) float f32x4;

// Fixed workspace layout (float offsets; all array bases 16B-aligned for float4)
enum : int {
  OFF_V      = 1040,
  OFF_M      = 1104,                  // unused since r15 (fold kept in LDS)
  OFF_EW1    = 5200,
  OFF_EB1    = 5520,
  OFF_NW1    = 5584,
  OFF_NB1    = 9744,
  OFF_NW2    = 9808,
  OFF_NB2    = 13904,
  OFF_OW1    = 13968,
  OFF_OB1    = 18064,
  OFF_OW2    = 18128,
  OFF_OB2    = 22224,
  OFF_OW3    = 22288,
  OFF_OB3    = 26384,
  OFF_OW4    = 26448,
  OFF_OB4    = 26576,
  OFF_EW2    = 26580,
  OFF_EB2    = 30676,
  OFF_FLAGS  = 30740,                 // 2 ints: [0]=ft (1=bf16), [1]=it (1=int64)
  OFF_W1T    = 30744,                 // 512 shorts (64 feats x 8 k)
  OFF_MT     = 31000,                 // 4096 shorts (M^T bf16)
  OFF_PREP   = 33048                  // rep: 8 pooled replicas * 16*64
};

struct WPtrs { const void* p[16]; };

__device__ __forceinline__ float cv(float v) { return v; }
__device__ __forceinline__ float cv(__hip_bfloat16 v) { return __bfloat162float(v); }
__device__ __forceinline__ float b2f(unsigned short u) {
  union { unsigned u32; float f; } c;
  c.u32 = ((unsigned)u) << 16;
  return c.f;
}
__device__ __forceinline__ unsigned short f2bu(float v) {   // cold path only
  union { __hip_bfloat16 b; unsigned short u; } c;
  c.b = __float2bfloat16(v);
  return c.u;
}
// fast RNE f32->bf16 (finite inputs): 3 VALU inst
__device__ __forceinline__ unsigned short fr(float v) {
  unsigned u = __float_as_uint(v);
  u += 0x7FFFu + ((u >> 16) & 1u);
  return (unsigned short)(u >> 16);
}
// relu + RNE-pack two floats into one dword via HW cvt_pk (lo = a, hi = b).
// r21-verified: replaces rndpack (9 VALU / 2 floats) with fmax x2 + 1 cvt_pk.
__device__ __forceinline__ unsigned cvtpk(float a, float b) {
  unsigned r;
  asm("v_cvt_pk_bf16_f32 %0, %1, %2"
      : "=v"(r) : "v"(fmaxf(a, 0.0f)), "v"(fmaxf(b, 0.0f)));
  return r;
}

// ---------------------------------------------------------------------------
// prep (r15-verified: 1024 threads, vectorized).
// ---------------------------------------------------------------------------
__global__ __launch_bounds__(1024) void prep_kernel(
    const void* xv, const void* eiv, WPtrs wp, float* ws)
{
  __shared__ int red[2];
  __shared__ int s_ft;
  __shared__ float ew2s[4096];
  __shared__ float nw1s[4096];
  const int t = threadIdx.x;
  const int lane = t & 63;

  if (t == 0) { red[0] = 0; red[1] = 0; }
  __syncthreads();
  {
    int big = 0;
    if (t < 512) {
      const unsigned el = (((const unsigned*)xv)[t] >> 7) & 0xFFu;
      big = (el >= 140u) ? 1 : 0;
    }
    #pragma unroll
    for (int o = 32; o > 0; o >>= 1) big += __shfl_xor(big, o);
    if (lane == 0 && big) atomicAdd(&red[0], big);
  }
  {
    int orv = ((const int*)eiv)[1 + 2 * t];
    #pragma unroll
    for (int o = 32; o > 0; o >>= 1) orv |= __shfl_xor(orv, o);
    if (lane == 0 && orv) atomicOr(&red[1], orv);
  }
  __syncthreads();
  if (t == 0) {
    const int ft = (red[0] < 8) ? 1 : 0;
    const int it = (red[1] == 0) ? 1 : 0;
    ((int*)(ws + OFF_FLAGS))[0] = ft;
    ((int*)(ws + OFF_FLAGS))[1] = it;
    s_ft = ft;
  }
  __syncthreads();
  const int ft = s_ft;

  const int sz[16]  = {320,64,4096,64,4160,64,4096,64,4096,64,4096,64,4096,64,128,2};
  const int dst[16] = {OFF_EW1,OFF_EB1,OFF_EW2,OFF_EB2,OFF_NW1,OFF_NB1,OFF_NW2,OFF_NB2,
                       OFF_OW1,OFF_OB1,OFF_OW2,OFF_OB2,OFF_OW3,OFF_OB3,OFF_OW4,OFF_OB4};
  for (int a = 0; a < 16; ++a) {
    const void* src = wp.p[a];
    float* d = ws + dst[a];
    const int n = sz[a];
    const int n4 = n >> 2;
    for (int i = t; i < n4; i += 1024) {
      float4 f;
      if (ft) {
        const ushort4 u4 = ((const ushort4*)src)[i];
        f.x = b2f(u4.x); f.y = b2f(u4.y); f.z = b2f(u4.z); f.w = b2f(u4.w);
      } else {
        f = ((const float4*)src)[i];
      }
      ((float4*)d)[i] = f;
      const int g = i << 2;
      if (a == 2) {
        ew2s[g] = f.x; ew2s[g + 1] = f.y; ew2s[g + 2] = f.z; ew2s[g + 3] = f.w;
      } else if (a == 4 && g >= 64) {
        nw1s[g - 64] = f.x; nw1s[g - 63] = f.y; nw1s[g - 62] = f.z; nw1s[g - 61] = f.w;
      }
    }
    for (int i = (n4 << 2) + t; i < n; i += 1024)
      d[i] = ft ? b2f(((const unsigned short*)src)[i]) : ((const float*)src)[i];
  }
  __syncthreads();

  // fold: M = EW2 @ NW1[1:], v = EB2 @ NW1[1:]  (4 outputs/thread)
  float mv[4];
  #pragma unroll
  for (int p = 0; p < 4; ++p) {
    const int idx = t + p * 1024;
    const int i = idx >> 6, j = idx & 63;
    float s = 0.0f;
    #pragma unroll 8
    for (int k = 0; k < 64; ++k)
      s = fmaf(ew2s[i * 64 + k], nw1s[k * 64 + j], s);
    mv[p] = s;
  }
  if (t < 64) {
    float s = 0.0f;
    #pragma unroll 8
    for (int k = 0; k < 64; ++k)
      s = fmaf(ws[OFF_EB2 + k], nw1s[k * 64 + t], s);
    ws[OFF_V + t] = s;
  }
  __syncthreads();
  #pragma unroll
  for (int p = 0; p < 4; ++p) ew2s[t + p * 1024] = mv[p];   // M now lives in ew2s
  __syncthreads();

  if (t < 64) {
    unsigned short* w1t = (unsigned short*)(ws + OFF_W1T);
    #pragma unroll
    for (int k = 0; k < 8; ++k) {
      float v = 0.0f;
      if (k < 5) v = ws[OFF_EW1 + k * 64 + t];
      else if (k == 5) v = ws[OFF_EB1 + t];
      w1t[t * 8 + k] = f2bu(v);
    }
  }
  unsigned short* mt = (unsigned short*)(ws + OFF_MT);
  #pragma unroll
  for (int p = 0; p < 4; ++p) {
    const int idx = t + p * 1024;
    const int n = idx >> 6, k = idx & 63;
    mt[idx] = f2bu(ew2s[k * 64 + n]);
  }
}

// ---------------------------------------------------------------------------
// count (+ merged bounds): per-block LDS histogram over COARSE GROUPS.
// r22-verified 2-pair batching; r23: 512 blocks.
// ---------------------------------------------------------------------------
template<typename IT>
__device__ __forceinline__ void count_impl(
    const IT* __restrict__ ei, const IT* __restrict__ bt,
    int* __restrict__ gcnt, int* __restrict__ endG, int* lh,
    const int E, const int N, const int NBG)
{
  const int t = threadIdx.x;
  const int b = blockIdx.x;
  for (int i = t; i < NBG; i += NCT) lh[i] = 0;
  {
    const int i = b * NCT + t;            // merged bounds pass (512K threads >= N)
    if (i < N) {
      const int g1 = (int)bt[i];
      if (i == 0) for (int g = 0; g < g1; ++g) endG[g] = 0;
      if (i == N - 1) {
        for (int g = g1; g < NGRAPH; ++g) endG[g] = N;
      } else {
        const int g2 = (int)bt[i + 1];
        for (int g = g1; g < g2; ++g) endG[g] = i + 1;
      }
    }
  }
  __syncthreads();
  const int per = (E + NCB - 1) / NCB;
  const int a = b * per;
  const int bnd = (a + per < E) ? (a + per) : E;
  const IT* col = ei + E;
  if ((E & 1) == 0) {                       // vector path (16B-aligned pairs)
    const int pa = (a + 1) >> 1;
    const int pb = bnd >> 1;
    if ((a & 1) && a < bnd && t == 0)
      atomicAdd(&lh[(int)col[a] >> 8], 1);
    if ((bnd & 1) && bnd - 1 >= a && t == NCT - 1)
      atomicAdd(&lh[(int)col[bnd - 1] >> 8], 1);
    for (int p = pa + t; p < pb; p += 2 * NCT) {
      const int p2 = p + NCT;
      const bool h2 = p2 < pb;
      int c0, c1, c2 = 0, c3 = 0;
      if constexpr (sizeof(IT) == 8) {
        const int4 v = ((const int4*)col)[p];
        c0 = v.x; c1 = v.z;
        if (h2) { const int4 w = ((const int4*)col)[p2]; c2 = w.x; c3 = w.z; }
      } else {
        const int2 v = ((const int2*)col)[p];
        c0 = v.x; c1 = v.y;
        if (h2) { const int2 w = ((const int2*)col)[p2]; c2 = w.x; c3 = w.y; }
      }
      atomicAdd(&lh[c0 >> 8], 1);
      atomicAdd(&lh[c1 >> 8], 1);
      if (h2) {
        atomicAdd(&lh[c2 >> 8], 1);
        atomicAdd(&lh[c3 >> 8], 1);
      }
    }
  } else {
    for (int e = a + t; e < bnd; e += NCT)
      atomicAdd(&lh[(int)col[e] >> 8], 1);
  }
  __syncthreads();
  for (int i = t; i < NBG; i += NCT) gcnt[(size_t)i * NCB + b] = lh[i];
}

__global__ __launch_bounds__(NCT) void count_kernel(
    const void* eiv, const void* batv, const float* ws,
    int* gcnt, int* endG, const int E, const int N, const int NBG)
{
  __shared__ int lh[MAXNB];
  const int it = ((const int*)(ws + OFF_FLAGS))[1];
  if (it) count_impl<long long>((const long long*)eiv, (const long long*)batv, gcnt, endG, lh, E, N, NBG);
  else    count_impl<int>((const int*)eiv, (const int*)batv, gcnt, endG, lh, E, N, NBG);
}

// ---------------------------------------------------------------------------
// scan (3-kernel parallel chain, r20-verified structure; r23: rows are
// NCB=512 wide -> 8 ints per lane, two int4 loads).
// ---------------------------------------------------------------------------
__global__ __launch_bounds__(256) void scan_tot_kernel(
    const int* __restrict__ gcnt, int* __restrict__ gstart, const int NBG)
{
  const int lane = threadIdx.x & 63;
  const int bkt = blockIdx.x * 4 + (threadIdx.x >> 6);
  if (bkt >= NBG) return;
  const int* row = gcnt + (size_t)bkt * NCB + lane * 8;
  const int4 v0 = *(const int4*)(row);
  const int4 v1 = *(const int4*)(row + 4);
  int s = v0.x + v0.y + v0.z + v0.w + v1.x + v1.y + v1.z + v1.w;
  #pragma unroll
  for (int off = 32; off > 0; off >>= 1) s += __shfl_xor(s, off);
  if (lane == 0) gstart[bkt] = s;
}

__global__ __launch_bounds__(256) void scan_pref_kernel(
    int* __restrict__ gstart, const int NBG)
{
  __shared__ int ps[256];
  const int t = threadIdx.x;
  const int seg = (NBG + 255) / 256;
  int s = 0;
  for (int i = 0; i < seg; ++i) {
    const int idx = t * seg + i;
    if (idx < NBG) s += gstart[idx];
  }
  ps[t] = s;
  __syncthreads();
  for (int off = 1; off < 256; off <<= 1) {
    const int v = (t >= off) ? ps[t - off] : 0;
    __syncthreads();
    ps[t] += v;
    __syncthreads();
  }
  int carry = ps[t] - s;
  for (int i = 0; i < seg; ++i) {
    const int idx = t * seg + i;
    if (idx < NBG) {
      const int c = gstart[idx];
      gstart[idx] = carry;
      carry += c;
    }
  }
  if (t == 255) gstart[NBG] = ps[255];
}

__global__ __launch_bounds__(256) void scan_row_kernel(
    int* __restrict__ gcnt, const int* __restrict__ gstart, const int NBG)
{
  const int lane = threadIdx.x & 63;
  const int bkt = blockIdx.x * 4 + (threadIdx.x >> 6);
  if (bkt >= NBG) return;
  int* row = gcnt + (size_t)bkt * NCB;
  const int4 v0 = *(const int4*)(row + lane * 8);
  const int4 v1 = *(const int4*)(row + lane * 8 + 4);
  const int ls = v0.x + v0.y + v0.z + v0.w + v1.x + v1.y + v1.z + v1.w;
  int s = ls;
  #pragma unroll
  for (int off = 1; off < 64; off <<= 1) {
    const int u = __shfl_up(s, off);
    if (lane >= off) s += u;
  }
  int e = s - ls + gstart[bkt];
  int4 o0, o1;
  o0.x = e; e += v0.x;
  o0.y = e; e += v0.y;
  o0.z = e; e += v0.z;
  o0.w = e; e += v0.w;
  o1.x = e; e += v1.x;
  o1.y = e; e += v1.y;
  o1.z = e; e += v1.z;
  o1.w = e;
  *(int4*)(row + lane * 8) = o0;
  *(int4*)(row + lane * 8 + 4) = o1;
}

// ---------------------------------------------------------------------------
// scatter pass 1: write bf16 payload recB[pos]={xr,a0,a1,a2} + cid[pos]=col&255
// sorted by COARSE GROUP only. r22-verified 2-pair batching; r23: 512 blocks.
// ---------------------------------------------------------------------------
template<typename FT, typename IT>
__device__ __forceinline__ void scat_one(
    const FT* __restrict__ x, const IT* __restrict__ ei, const FT* __restrict__ ea,
    int* lb, ushort4* __restrict__ recB, unsigned char* __restrict__ cid,
    const int E, const int e, const int gb0, const int gb1, const int cap)
{
  const int c = (int)ei[(size_t)E + e];
  const int grp = c >> 8;
  if (grp >= gb0 && grp < gb1) {
    const int pos = atomicAdd(&lb[grp - gb0], 1);
    if (pos < cap) {
      const int r = (int)ei[e];
      ushort4 rv;
      rv.x = fr(cv(x[r]));
      rv.y = fr(cv(ea[(size_t)3 * e + 0]));
      rv.z = fr(cv(ea[(size_t)3 * e + 1]));
      rv.w = fr(cv(ea[(size_t)3 * e + 2]));
      recB[pos] = rv;
      cid[pos] = (unsigned char)(c & 255);
    }
  }
}

template<typename FT, typename IT>
__device__ __forceinline__ void scatter_impl(
    const FT* __restrict__ x, const IT* __restrict__ ei, const FT* __restrict__ ea,
    const int* __restrict__ gcnt, const int* __restrict__ gstart,
    ushort4* __restrict__ recB, unsigned char* __restrict__ cid, int* lb,
    const int E, const int gb0, const int gb1, const int cap)
{
  const int t = threadIdx.x;
  const int b = blockIdx.x;
  __shared__ int sbase;
  if (t == 0) sbase = gstart[gb0];
  __syncthreads();
  const int base = sbase;
  const int gcount = gb1 - gb0;
  for (int i = t; i < gcount; i += NCT) lb[i] = gcnt[(size_t)(gb0 + i) * NCB + b] - base;
  __syncthreads();

  const int per = (E + NCB - 1) / NCB;
  const int a = b * per;
  const int bnd = (a + per < E) ? (a + per) : E;
  for (int e = a + t; e < bnd; e += NCT)
    scat_one<FT, IT>(x, ei, ea, lb, recB, cid, E, e, gb0, gb1, cap);
}

// emit one edge's record from pre-loaded values
__device__ __forceinline__ void emit_rec(
    int* lb, ushort4* __restrict__ recB, unsigned char* __restrict__ cid,
    const int c, const unsigned short xr,
    const unsigned short a0, const unsigned short a1, const unsigned short a2,
    const int gb0, const int gb1, const int cap)
{
  const int g = c >> 8;
  if (g >= gb0 && g < gb1) {
    const int pos = atomicAdd(&lb[g - gb0], 1);
    if (pos < cap) {
      ushort4 rv;
      rv.x = xr; rv.y = a0; rv.z = a1; rv.w = a2;
      recB[pos] = rv;
      cid[pos] = (unsigned char)(c & 255);
    }
  }
}

// bf16 + even-E fast path: 2-pair batching, vector loads, raw bit payload copy.
template<typename IT>
__device__ __forceinline__ void scatter_fast(
    const unsigned short* __restrict__ x, const IT* __restrict__ ei,
    const void* __restrict__ eav,
    const int* __restrict__ gcnt, const int* __restrict__ gstart,
    ushort4* __restrict__ recB, unsigned char* __restrict__ cid, int* lb,
    const int E, const int gb0, const int gb1, const int cap)
{
  const int t = threadIdx.x;
  const int b = blockIdx.x;
  __shared__ int sbase2;
  if (t == 0) sbase2 = gstart[gb0];
  __syncthreads();
  const int base = sbase2;
  const int gcount = gb1 - gb0;
  for (int i = t; i < gcount; i += NCT) lb[i] = gcnt[(size_t)(gb0 + i) * NCB + b] - base;
  __syncthreads();

  const int per = (E + NCB - 1) / NCB;
  const int a = b * per;
  const int bnd = (a + per < E) ? (a + per) : E;
  const int pa = (a + 1) >> 1;
  const int pb = bnd >> 1;

  // head/tail odd edges via scalar helper (bf16 view)
  const __hip_bfloat16* xb = (const __hip_bfloat16*)x;
  const __hip_bfloat16* eab = (const __hip_bfloat16*)eav;
  if ((a & 1) && a < bnd && t == 0)
    scat_one<__hip_bfloat16, IT>(xb, ei, eab, lb, recB, cid, E, a, gb0, gb1, cap);
  if ((bnd & 1) && bnd - 1 >= a && t == NCT - 1)
    scat_one<__hip_bfloat16, IT>(xb, ei, eab, lb, recB, cid, E, bnd - 1, gb0, gb1, cap);

  const IT* col = ei + E;
  for (int p = pa + t; p < pb; p += 2 * NCT) {
    const int p2 = p + NCT;
    const bool h2 = p2 < pb;

    // batch A loads
    int c0, c1, r0, r1;
    if constexpr (sizeof(IT) == 8) {
      const int4 vc = ((const int4*)col)[p];
      c0 = vc.x; c1 = vc.z;
      const int4 vr = ((const int4*)ei)[p];
      r0 = vr.x; r1 = vr.z;
    } else {
      const int2 vc = ((const int2*)col)[p];
      c0 = vc.x; c1 = vc.y;
      const int2 vr = ((const int2*)ei)[p];
      r0 = vr.x; r1 = vr.y;
    }
    const uint3 d = ((const uint3*)eav)[p];

    // batch B loads (independent; issue before any dependent use)
    int c0b = 0, c1b = 0, r0b = 0, r1b = 0;
    uint3 db = make_uint3(0, 0, 0);
    if (h2) {
      if constexpr (sizeof(IT) == 8) {
        const int4 vc = ((const int4*)col)[p2];
        c0b = vc.x; c1b = vc.z;
        const int4 vr = ((const int4*)ei)[p2];
        r0b = vr.x; r1b = vr.z;
      } else {
        const int2 vc = ((const int2*)col)[p2];
        c0b = vc.x; c1b = vc.y;
        const int2 vr = ((const int2*)ei)[p2];
        r0b = vr.x; r1b = vr.y;
      }
      db = ((const uint3*)eav)[p2];
    }

    // x gathers for all 4 edges (issue together)
    const unsigned short x0 = x[r0];
    const unsigned short x1 = x[r1];
    const unsigned short x0b = h2 ? x[r0b] : (unsigned short)0;
    const unsigned short x1b = h2 ? x[r1b] : (unsigned short)0;

    emit_rec(lb, recB, cid, c0, x0,
             (unsigned short)(d.x & 0xFFFFu), (unsigned short)(d.x >> 16),
             (unsigned short)(d.y & 0xFFFFu), gb0, gb1, cap);
    emit_rec(lb, recB, cid, c1, x1,
             (unsigned short)(d.y >> 16), (unsigned short)(d.z & 0xFFFFu),
             (unsigned short)(d.z >> 16), gb0, gb1, cap);
    if (h2) {
      emit_rec(lb, recB, cid, c0b, x0b,
               (unsigned short)(db.x & 0xFFFFu), (unsigned short)(db.x >> 16),
               (unsigned short)(db.y & 0xFFFFu), gb0, gb1, cap);
      emit_rec(lb, recB, cid, c1b, x1b,
               (unsigned short)(db.y >> 16), (unsigned short)(db.z & 0xFFFFu),
               (unsigned short)(db.z >> 16), gb0, gb1, cap);
    }
  }
}

__global__ __launch_bounds__(NCT) void scatter_kernel(
    const void* xv, const void* eiv, const void* eav, const float* ws,
    const int* gcnt, const int* gstart, ushort4* recB, unsigned char* cid,
    const int E, const int gb0, const int gb1, const int cap)
{
  __shared__ int lb[MAXNB];
  const int* fl = (const int*)(ws + OFF_FLAGS);
  const int ft = fl[0], it = fl[1];
  if (ft && ((E & 1) == 0)) {
    if (it) scatter_fast<long long>((const unsigned short*)xv, (const long long*)eiv, eav, gcnt, gstart, recB, cid, lb, E, gb0, gb1, cap);
    else    scatter_fast<int>((const unsigned short*)xv, (const int*)eiv, eav, gcnt, gstart, recB, cid, lb, E, gb0, gb1, cap);
  } else if (ft) {
    if (it) scatter_impl<__hip_bfloat16, long long>((const __hip_bfloat16*)xv, (const long long*)eiv, (const __hip_bfloat16*)eav, gcnt, gstart, recB, cid, lb, E, gb0, gb1, cap);
    else    scatter_impl<__hip_bfloat16, int>((const __hip_bfloat16*)xv, (const int*)eiv, (const __hip_bfloat16*)eav, gcnt, gstart, recB, cid, lb, E, gb0, gb1, cap);
  } else {
    if (it) scatter_impl<float, long long>((const float*)xv, (const long long*)eiv, (const float*)eav, gcnt, gstart, recB, cid, lb, E, gb0, gb1, cap);
    else    scatter_impl<float, int>((const float*)xv, (const int*)eiv, (const float*)eav, gcnt, gstart, recB, cid, lb, E, gb0, gb1, cap);
  }
}

// ---------------------------------------------------------------------------
// sort pass 2: one block per coarse group; LDS-staged in-place fine sort.
// ---------------------------------------------------------------------------
__global__ __launch_bounds__(SORT_T) void sort_kernel(
    ushort4* __restrict__ recB, unsigned char* __restrict__ cid,
    const int* __restrict__ gstart, int* __restrict__ bstartF,
    const int NB, const int gr0, const int cap)
{
  __shared__ unsigned sru[SORT_CHUNK * 2];     // 102.4 KB record payload
  __shared__ unsigned char sc[SORT_CHUNK];     // 12.8 KB keys
  __shared__ int h2[16][GB];                   // per-wave histograms
  __shared__ int fs[GB];
  __shared__ int cur[GB];

  const int t = threadIdx.x;
  const int lane = t & 63;
  const int wav = t >> 6;
  const int g = gr0 + (int)blockIdx.x;

  const int base0 = gstart[gr0];
  int rb = gstart[g] - base0;
  int re = gstart[g + 1] - base0;
  if (rb > cap) rb = cap;
  if (re > cap) re = cap;
  int cnt = re - rb;
  if (cnt > SORT_CHUNK) cnt = SORT_CHUNK;

  if (t < 16 * GB) ((int*)h2)[t] = 0;
  __syncthreads();

  // stage to LDS + per-wave histogram (ballot-aggregated, no atomics)
  for (int i = t; i < cnt; i += SORT_T) {
    const ushort4 r = recB[rb + i];
    sru[2 * i]     = (unsigned)r.x | ((unsigned)r.y << 16);
    sru[2 * i + 1] = (unsigned)r.z | ((unsigned)r.w << 16);
    const unsigned char c = cid[rb + i];
    sc[i] = c;
    const int kk = c >> 5;
    unsigned long long mym = 0;
    #pragma unroll
    for (int k = 0; k < GB; ++k) {
      const unsigned long long bk = __ballot(kk == k);
      if (kk == k) mym = bk;
    }
    if ((mym & (((unsigned long long)1 << lane) - 1ull)) == 0)   // leader per key
      h2[wav][kk] += (int)__builtin_popcountll(mym);
  }
  __syncthreads();

  if (t == 0) {
    int acc = 0;
    for (int k = 0; k < GB; ++k) {
      int s = 0;
      #pragma unroll
      for (int w = 0; w < 16; ++w) s += h2[w][k];
      fs[k] = acc;
      cur[k] = acc;
      acc += s;
    }
  }
  __syncthreads();

  // fine bucket starts (absolute)
  if (t <= GB) {
    const int bk = g * GB + t;
    if (bk <= NB) bstartF[bk] = base0 + rb + ((t == GB) ? cnt : fs[t]);
  }

  // in-place scatter to final bucket-sorted positions
  for (int i = t; i < cnt; i += SORT_T) {
    const unsigned char c = sc[i];
    const int kk = c >> 5;
    unsigned long long mym = 0;
    #pragma unroll
    for (int k = 0; k < GB; ++k) {
      const unsigned long long bk = __ballot(kk == k);
      if (kk == k) mym = bk;
    }
    const int lead = (int)__builtin_ctzll(mym);
    const int off = (int)__builtin_popcountll(mym & (((unsigned long long)1 << lane) - 1ull));
    int bas = 0;
    if (lane == lead) bas = atomicAdd(&cur[kk], (int)__builtin_popcountll(mym));
    bas = __shfl(bas, lead);
    const int pos = rb + bas + off;
    const unsigned a = sru[2 * i], b = sru[2 * i + 1];
    ushort4 rv;
    rv.x = (unsigned short)(a & 0xFFFFu); rv.y = (unsigned short)(a >> 16);
    rv.z = (unsigned short)(b & 0xFFFFu); rv.w = (unsigned short)(b >> 16);
    recB[pos] = rv;
    cid[pos] = (unsigned char)(c & 31);
  }
}

// ---------------------------------------------------------------------------
// fused (cooperative MFMA, r19/r21-verified): pair-phase schedule, incremental
// one-hot, reg-held A1, scalar prefetch, cvt_pk bf16 conversion.
// ---------------------------------------------------------------------------

#define FUSED_H(J, RV, CC)                                                       \
    if ((J) < jmax) {                                                            \
      short* HT = sHT + ((J) & 1) * 4608;                                        \
      short8 a1;                                                                 \
      if (quad == 0) {                                                           \
        const bool vv = (CC) < 32;                                               \
        a1[0] = (short)(RV).x;                                                   \
        a1[1] = vv ? (short)xlsb[(CC)] : (short)0;                               \
        a1[2] = (short)(RV).y; a1[3] = (short)(RV).z; a1[4] = (short)(RV).w;     \
        a1[5] = vv ? (short)0x3F80 : (short)0;                                   \
        a1[6] = 0; a1[7] = 0;                                                    \
      } else {                                                                   \
        a1[0]=0; a1[1]=0; a1[2]=0; a1[3]=0; a1[4]=0; a1[5]=0; a1[6]=0; a1[7]=0;  \
      }                                                                          \
      f32x4 Hc0 = __builtin_amdgcn_mfma_f32_16x16x32_bf16(a1, B1[0], (f32x4)0.0f, 0, 0, 0); \
      f32x4 Hc1 = __builtin_amdgcn_mfma_f32_16x16x32_bf16(a1, B1[1], (f32x4)0.0f, 0, 0, 0); \
      f32x4 Hc2 = __builtin_amdgcn_mfma_f32_16x16x32_bf16(a1, B1[2], (f32x4)0.0f, 0, 0, 0); \
      f32x4 Hc3 = __builtin_amdgcn_mfma_f32_16x16x32_bf16(a1, B1[3], (f32x4)0.0f, 0, 0, 0); \
      uint2 pk0, pk1, pk2, pk3;                                                  \
      pk0.x = cvtpk(Hc0[0], Hc0[1]); pk0.y = cvtpk(Hc0[2], Hc0[3]);              \
      pk1.x = cvtpk(Hc1[0], Hc1[1]); pk1.y = cvtpk(Hc1[2], Hc1[3]);              \
      pk2.x = cvtpk(Hc2[0], Hc2[1]); pk2.y = cvtpk(Hc2[2], Hc2[3]);              \
      pk3.x = cvtpk(Hc3[0], Hc3[1]); pk3.y = cvtpk(Hc3[2], Hc3[3]);              \
      *(uint2*)(HT + ( 0 + l15) * 72 + 16 * wav + quad * 4) = pk0;               \
      *(uint2*)(HT + (16 + l15) * 72 + 16 * wav + quad * 4) = pk1;               \
      *(uint2*)(HT + (32 + l15) * 72 + 16 * wav + quad * 4) = pk2;               \
      *(uint2*)(HT + (48 + l15) * 72 + 16 * wav + quad * 4) = pk3;               \
    }

#define FUSED_PV(J)                                                             \
    if ((J) < jmax) {                                                           \
      const short* HT = sHT + ((J) & 1) * 4608;                                 \
      const short* aj = a2L + (J) * 2304;                                       \
      _Pragma("unroll")                                                         \
      for (int q = 0; q < 2; ++q) {                                             \
        const short8 a20 = *(const short8*)(aj + l15 * 72 + 32 * q + 8 * quad); \
        const short8 a21 = *(const short8*)(aj + (16 + l15) * 72 + 32 * q + 8 * quad); \
        const short8 b2  = *(const short8*)(HT + (16 * wav + l15) * 72 + 32 * q + quad * 8); \
        C2[0] = __builtin_amdgcn_mfma_f32_16x16x32_bf16(a20, b2, C2[0], 0, 0, 0);\
        C2[1] = __builtin_amdgcn_mfma_f32_16x16x32_bf16(a21, b2, C2[1], 0, 0, 0);\
        C3[0] = __builtin_amdgcn_mfma_f32_16x16x32_bf16(a20, ONES8, C3[0], 0, 0, 0); \
        C3[1] = __builtin_amdgcn_mfma_f32_16x16x32_bf16(a21, ONES8, C3[1], 0, 0, 0); \
      }                                                                         \
    }

template<typename FT, typename IT>
__device__ __forceinline__ void fused_impl(
    const FT* __restrict__ x, const IT* __restrict__ batch,
    const float* __restrict__ ws, const int* __restrict__ bstart,
    const ushort4* __restrict__ recB, const unsigned char* __restrict__ cid,
    float* __restrict__ rep,
    short* sHT, short* a2L,
    float* xls, unsigned short* xlsb, int* sbi,
    const int N, const int gb0, const int cap)
{
  const int t = threadIdx.x;
  const int lane = t & 63;
  const int quad = lane >> 4;
  const int l15 = lane & 15;
  const int wav = t >> 6;
  const int bucket = gb0 + blockIdx.x;

  // initial full zero of a2L (once; afterwards incrementally maintained)
  {
    unsigned long long* az = (unsigned long long*)a2L;
    #pragma unroll
    for (int z = 0; z < 9; ++z) az[t + z * 256] = 0ull;
  }
  if (t < BN) {
    const int n = bucket * BN + t;
    const float xvv = (n < N) ? cv(x[n]) : 0.0f;
    xls[t] = xvv;
    xlsb[t] = fr(xvv);
  }
  if (t == 0) {
    const int nf = bucket * BN, nl = bucket * BN + BN - 1;
    sbi[0] = (int)batch[(nf < N) ? nf : (N - 1)];
    sbi[1] = (int)batch[(nl < N) ? nl : (N - 1)];
    sbi[2] = bstart[gb0];
  }
  __syncthreads();

  const unsigned short* w1t = (const unsigned short*)(ws + OFF_W1T);
  short8 B1[4];
  #pragma unroll
  for (int tn = 0; tn < 4; ++tn) {
    short8 z; for (int j = 0; j < 8; ++j) z[j] = 0;
    if (quad == 0) z = *(const short8*)(w1t + (16 * tn + l15) * 8);
    B1[tn] = z;
  }
  short8 ONES8;
  #pragma unroll
  for (int j = 0; j < 8; ++j) ONES8[j] = (short)0x3F80;

  const int base = sbi[2];
  int s0 = bstart[bucket] - base;
  int e0 = bstart[bucket + 1] - base;
  if (s0 > cap) s0 = cap;
  if (e0 > cap) e0 = cap;

  f32x4 C2[2]; C2[0] = (f32x4)0.0f; C2[1] = (f32x4)0.0f;
  f32x4 C3[2]; C3[0] = (f32x4)0.0f; C3[1] = (f32x4)0.0f;

  const int nedge = e0 - s0;
  const int nst = (nedge + 255) >> 8;

  // quad-0 lane (wav,l15) owns edges 64*j + 16*wav + l15 of each stage.
  const ushort4 uz = make_ushort4(0, 0, 0, 0);
  ushort4 rv0 = uz, rv1 = uz, rv2 = uz, rv3 = uz;
  int c0 = 255, c1 = 255, c2 = 255, c3 = 255;
  int cp0 = 255, cp1 = 255, cp2 = 255, cp3 = 255;   // previously-set one-hot col
  if (nst > 0 && quad == 0) {
    int idx;
    idx = s0 +   0 + 16 * wav + l15; if (idx < e0) { rv0 = recB[idx]; c0 = (int)cid[idx]; }
    idx = s0 +  64 + 16 * wav + l15; if (idx < e0) { rv1 = recB[idx]; c1 = (int)cid[idx]; }
    idx = s0 + 128 + 16 * wav + l15; if (idx < e0) { rv2 = recB[idx]; c2 = (int)cid[idx]; }
    idx = s0 + 192 + 16 * wav + l15; if (idx < e0) { rv3 = recB[idx]; c3 = (int)cid[idx]; }
  }

  for (int st = 0; st < nst; ++st) {
    const int m = nedge - st * 256;
    const int jmax = (m >= 256) ? 4 : ((m + 63) >> 6);

    // incremental one-hot update (same-thread slot ownership)
    if (quad == 0) {
      const int row = 16 * wav + l15;
      if (cp0 != c0) { if (cp0 < 32) a2L[0 * 2304 + cp0 * 72 + row] = 0;
                       if (c0  < 32) a2L[0 * 2304 + c0  * 72 + row] = (short)0x3F80; }
      if (cp1 != c1) { if (cp1 < 32) a2L[1 * 2304 + cp1 * 72 + row] = 0;
                       if (c1  < 32) a2L[1 * 2304 + c1  * 72 + row] = (short)0x3F80; }
      if (cp2 != c2) { if (cp2 < 32) a2L[2 * 2304 + cp2 * 72 + row] = 0;
                       if (c2  < 32) a2L[2 * 2304 + c2  * 72 + row] = (short)0x3F80; }
      if (cp3 != c3) { if (cp3 < 32) a2L[3 * 2304 + cp3 * 72 + row] = 0;
                       if (c3  < 32) a2L[3 * 2304 + c3  * 72 + row] = (short)0x3F80; }
    }
    cp0 = c0; cp1 = c1; cp2 = c2; cp3 = c3;

    // prefetch next stage into scalar regs; HBM latency hides under MFMA
    ushort4 nv0 = uz, nv1 = uz, nv2 = uz, nv3 = uz;
    int n0 = 255, n1 = 255, n2 = 255, n3 = 255;
    if (st + 1 < nst && quad == 0) {
      const int nb = s0 + (st + 1) * 256 + 16 * wav + l15;
      int idx;
      idx = nb;       if (idx < e0) { nv0 = recB[idx]; n0 = (int)cid[idx]; }
      idx = nb +  64; if (idx < e0) { nv1 = recB[idx]; n1 = (int)cid[idx]; }
      idx = nb + 128; if (idx < e0) { nv2 = recB[idx]; n2 = (int)cid[idx]; }
      idx = nb + 192; if (idx < e0) { nv3 = recB[idx]; n3 = (int)cid[idx]; }
    }

    FUSED_H(0, rv0, c0)
    FUSED_H(1, rv1, c1)
    __syncthreads();
    FUSED_PV(0)
    FUSED_PV(1)
    __syncthreads();
    if (jmax > 2) {
      FUSED_H(2, rv2, c2)
      FUSED_H(3, rv3, c3)
      __syncthreads();
      FUSED_PV(2)
      FUSED_PV(3)
      __syncthreads();
    }
    rv0 = nv0; c0 = n0; rv1 = nv1; c1 = n1;
    rv2 = nv2; c2 = n2; rv3 = nv3; c3 = n3;
  }

  short* aggB = a2L;   // overlay rows 0..31 (4608B); a2L dead after main loop
  #pragma unroll
  for (int tm2 = 0; tm2 < 2; ++tm2) {
    #pragma unroll
    for (int r = 0; r < 4; ++r)
      aggB[(16 * tm2 + quad * 4 + r) * 72 + 16 * wav + l15] = (short)fr(C2[tm2][r]);
  }
  __syncthreads();

  const unsigned short* mt = (const unsigned short*)(ws + OFF_MT);
  f32x4 D[2]; D[0] = (f32x4)0.0f; D[1] = (f32x4)0.0f;
  #pragma unroll
  for (int q2 = 0; q2 < 2; ++q2) {
    const short8 bb = *(const short8*)(mt + (16 * wav + l15) * 64 + 32 * q2 + quad * 8);
    #pragma unroll
    for (int tm2 = 0; tm2 < 2; ++tm2) {
      const short8 aa = *(const short8*)(aggB + (16 * tm2 + l15) * 72 + 32 * q2 + quad * 8);
      D[tm2] = __builtin_amdgcn_mfma_f32_16x16x32_bf16(aa, bb, D[tm2], 0, 0, 0);
    }
  }

  const int n = 16 * wav + l15;
  const float c1n = ws[OFF_NW1 + n];
  const float vn  = ws[OFF_V + n];
  const float bn  = ws[OFF_NB1 + n];
  float* myrep = rep + (size_t)(bucket & 7) * (NGRAPH * 64);
  const bool multi = (sbi[0] != sbi[1]);

  if (!multi) {
    // fast path: whole bucket in one graph -> quad-reduce + 1 atomic per (g,n)
    float hs = 0.0f;
    #pragma unroll
    for (int tm2 = 0; tm2 < 2; ++tm2) {
      #pragma unroll
      for (int r = 0; r < 4; ++r) {
        const int mrow = 16 * tm2 + quad * 4 + r;
        const int ng = bucket * BN + mrow;
        if (ng < N)
          hs += fmaxf(D[tm2][r] + xls[mrow] * c1n + C3[tm2][r] * vn + bn, 0.0f);
      }
    }
    hs += __shfl_xor(hs, 16);
    hs += __shfl_xor(hs, 32);
    if (quad == 0) unsafeAtomicAdd(&myrep[sbi[0] * 64 + n], hs);
  } else {
    float* pooledL = (float*)((char*)a2L + 4608);   // behind aggB rows, 4096B
    for (int i = t; i < NGRAPH * 64; i += 256) pooledL[i] = 0.0f;
    __syncthreads();
    #pragma unroll
    for (int tm2 = 0; tm2 < 2; ++tm2) {
      #pragma unroll
      for (int r = 0; r < 4; ++r) {
        const int mrow = 16 * tm2 + quad * 4 + r;
        const int ng = bucket * BN + mrow;
        if (ng < N) {
          const float h = fmaxf(D[tm2][r] + xls[mrow] * c1n + C3[tm2][r] * vn + bn, 0.0f);
          const int g = (int)batch[ng];
          atomicAdd(&pooledL[g * 64 + n], h);
        }
      }
    }
    __syncthreads();
    for (int g = sbi[0] + wav; g <= sbi[1]; g += 4)
      unsafeAtomicAdd(&myrep[g * 64 + lane], pooledL[g * 64 + lane]);
  }
}

__global__ __launch_bounds__(256, 4) void fused_kernel(
    const void* xv, const void* batv, const float* ws, const int* bstart,
    const ushort4* recB, const unsigned char* cid, float* rep,
    const int N, const int gb0, const int cap)
{
  // carved LDS (37.1 KB -> 4 blocks/CU): sHT dbuf 18432 | a2L/aggB/pooledL 18432 | misc
  __shared__ __align__(16) unsigned char smem[37072];
  short* sHT = (short*)smem;
  short* a2L = (short*)(smem + 18432);
  float* xls = (float*)(smem + 36864);
  unsigned short* xlsb = (unsigned short*)(smem + 36992);
  int* sbi = (int*)(smem + 37056);

  const int* fl = (const int*)(ws + OFF_FLAGS);
  const int ft = fl[0], it = fl[1];
  if (ft) {
    if (it) fused_impl<__hip_bfloat16, long long>((const __hip_bfloat16*)xv, (const long long*)batv, ws, bstart, recB, cid, rep, sHT, a2L, xls, xlsb, sbi, N, gb0, cap);
    else    fused_impl<__hip_bfloat16, int>((const __hip_bfloat16*)xv, (const int*)batv, ws, bstart, recB, cid, rep, sHT, a2L, xls, xlsb, sbi, N, gb0, cap);
  } else {
    if (it) fused_impl<float, long long>((const float*)xv, (const long long*)batv, ws, bstart, recB, cid, rep, sHT, a2L, xls, xlsb, sbi, N, gb0, cap);
    else    fused_impl<float, int>((const float*)xv, (const int*)batv, ws, bstart, recB, cid, rep, sHT, a2L, xls, xlsb, sbi, N, gb0, cap);
  }
}

// ---------------------------------------------------------------------------
// head: reduce 8 pooled replicas; cnt from precomputed endG; dense head.
// ---------------------------------------------------------------------------
__global__ __launch_bounds__(256) void head_kernel(
    const float* ws, const float* rep, const int* __restrict__ endG,
    void* outv, const int N)
{
  __shared__ float P[NGRAPH][HID];
  __shared__ float A[NGRAPH][HID];
  __shared__ float B[NGRAPH][HID];
  __shared__ int endL[NGRAPH];

  const int t = threadIdx.x;
  const int j = t & 63;
  const int gq = t >> 6;

  if (t < NGRAPH) endL[t] = endG[t];

  #pragma unroll
  for (int gi = 0; gi < 4; ++gi) {
    const int g = gq + gi * 4;
    float s = 0.0f;
    #pragma unroll
    for (int r = 0; r < 8; ++r)
      s += rep[(size_t)r * (NGRAPH * 64) + g * 64 + j];
    P[g][j] = s;
  }
  __syncthreads();

  {
    const float bj = ws[OFF_NB2 + j];
    #pragma unroll
    for (int gi = 0; gi < 4; ++gi) {
      const int g = gq + gi * 4;
      const float cg = (float)(endL[g] - (g ? endL[g - 1] : 0));
      float s = cg * bj;
      #pragma unroll 8
      for (int k = 0; k < HID; ++k)
        s = fmaf(P[g][k], ws[OFF_NW2 + k * HID + j], s);
      A[g][j] = s;
    }
  }
  __syncthreads();

  const int wOff[3] = {OFF_OW1, OFF_OW2, OFF_OW3};
  const int bOff[3] = {OFF_OB1, OFF_OB2, OFF_OB3};
  for (int L = 0; L < 3; ++L) {
    float (*In)[HID]  = (L & 1) ? B : A;
    float (*Out)[HID] = (L & 1) ? A : B;
    const float bj = ws[bOff[L] + j];
    #pragma unroll
    for (int gi = 0; gi < 4; ++gi) {
      const int g = gq + gi * 4;
      float s = bj;
      #pragma unroll 8
      for (int k = 0; k < HID; ++k)
        s = fmaf(In[g][k], ws[wOff[L] + k * HID + j], s);
      Out[g][j] = fmaxf(s, 0.0f);
    }
    __syncthreads();
  }

  if (t < 32) {
    const int g = t >> 1, d = t & 1;
    float s = ws[OFF_OB4 + d];
    #pragma unroll 8
    for (int k = 0; k < HID; ++k)
      s = fmaf(B[g][k], ws[OFF_OW4 + k * 2 + d], s);
    const int ft = ((const int*)(ws + OFF_FLAGS))[0];
    if (ft) ((__hip_bfloat16*)outv)[g * 2 + d] = __float2bfloat16(s);
    else    ((float*)outv)[g * 2 + d] = s;
  }
}

extern "C" void kernel_launch(void* const* d_in, const int* in_sizes, int n_in,
                              void* d_out, int out_size, void* d_ws, size_t ws_size,
                              hipStream_t stream)
{
  const void* xv   = d_in[0];
  const void* eiv  = d_in[1];
  const void* eav  = d_in[2];
  const void* batv = d_in[3];

  WPtrs wp;
  for (int a = 0; a < 16; ++a) wp.p[a] = d_in[4 + a];

  const int N = in_sizes[0];
  const int E = in_sizes[1] / 2;
  const int NB = (N + BN - 1) / BN;
  const int NBG = (NB + GB - 1) / GB;
  if (NB > MAXNB) return;

  float* ws    = (float*)d_ws;
  float* rep   = ws + OFF_PREP;                            // 8*1024 floats
  int* gstart  = (int*)(rep + 8 * NGRAPH * 64);            // NBG+1 ints
  int* bstartF = gstart + NBG + 1;                         // NB+2 ints
  int* endG    = bstartF + NB + 2;                         // 16 ints
  int* gcnt    = endG + NGRAPH;                            // NBG*NCB ints

  size_t recOffB = ((size_t)((char*)(gcnt + (size_t)NBG * NCB) - (char*)d_ws) + 15) & ~(size_t)15;

  int G = -1; long long cap = 0;
  for (int g = 1; g <= 64; ++g) {
    const long long c = (long long)E / g + E / 32 + 8192;
    if (recOffB + (size_t)c * 9 <= ws_size) { G = g; cap = c; break; }
  }
  if (G < 0) return;

  ushort4* recB = (ushort4*)((char*)d_ws + recOffB);
  unsigned char* cid = (unsigned char*)(recB + cap);
  const int gsz = (NBG + G - 1) / G;
  const int sblk = (NBG + 3) / 4;

  (void)hipMemsetAsync(rep, 0, (size_t)(8 * NGRAPH * 64) * 4, stream);

  prep_kernel<<<1, 1024, 0, stream>>>(xv, eiv, wp, ws);
  count_kernel<<<NCB, NCT, 0, stream>>>(eiv, batv, ws, gcnt, endG, E, N, NBG);
  scan_tot_kernel<<<sblk, 256, 0, stream>>>(gcnt, gstart, NBG);
  scan_pref_kernel<<<1, 256, 0, stream>>>(gstart, NBG);
  scan_row_kernel<<<sblk, 256, 0, stream>>>(gcnt, gstart, NBG);

  for (int g = 0; g < G; ++g) {
    const int gr0 = g * gsz;
    const int gr1 = (gr0 + gsz < NBG) ? (gr0 + gsz) : NBG;
    if (gr0 >= gr1) break;
    scatter_kernel<<<NCB, NCT, 0, stream>>>(xv, eiv, eav, ws, gcnt, gstart,
                                            recB, cid, E, gr0, gr1, (int)cap);
    sort_kernel<<<gr1 - gr0, SORT_T, 0, stream>>>(recB, cid, gstart, bstartF,
                                                  NB, gr0, (int)cap);
    const int b0 = gr0 * GB;
    const int b1 = (gr1 * GB < NB) ? (gr1 * GB) : NB;
    fused_kernel<<<b1 - b0, 256, 0, stream>>>(xv, batv, ws, bstartF, recB, cid,
                                              rep, N, b0, (int)cap);
  }

  head_kernel<<<1, 256, 0, stream>>>(ws, rep, endG, d_out, N);
}